// Round 10
// baseline (999.301 us; speedup 1.0000x reference)
//
#include <hip/hip_runtime.h>
#include <cstdint>
#include <cstddef>

#define NN 20000
#define NE 320000
#define SBUF 10240000   // shorts per [node][512] buffer

typedef float f32x4 __attribute__((ext_vector_type(4)));
typedef short s16x8 __attribute__((ext_vector_type(8)));
typedef unsigned short us;

__device__ __forceinline__ us f2bf(float x){
    unsigned u = __float_as_uint(x);
    unsigned r = (u + 0x7fffu + ((u >> 16) & 1u)) >> 16;
    return (us)r;
}
__device__ __forceinline__ float bf2f(us s){
    return __uint_as_float(((unsigned)s) << 16);
}

__device__ __forceinline__ void upd8(uint4 v, float w, float* ao, float* ai){
    float f0=__uint_as_float(v.x<<16), f1=__uint_as_float(v.x&0xffff0000u);
    float f2=__uint_as_float(v.y<<16), f3=__uint_as_float(v.y&0xffff0000u);
    float f4=__uint_as_float(v.z<<16), f5=__uint_as_float(v.z&0xffff0000u);
    float f6=__uint_as_float(v.w<<16), f7=__uint_as_float(v.w&0xffff0000u);
    ao[0]=fmaf(w,f0,ao[0]); ao[1]=fmaf(w,f1,ao[1]); ao[2]=fmaf(w,f2,ao[2]); ao[3]=fmaf(w,f3,ao[3]);
    ao[4]=fmaf(w,f4,ao[4]); ao[5]=fmaf(w,f5,ao[5]); ao[6]=fmaf(w,f6,ao[6]); ao[7]=fmaf(w,f7,ao[7]);
    ai[0]+=f0; ai[1]+=f1; ai[2]+=f2; ai[3]+=f3; ai[4]+=f4; ai[5]+=f5; ai[6]+=f6; ai[7]+=f7;
}
__device__ __forceinline__ void updw(uint4 v, float w, float* a){
    float f0=__uint_as_float(v.x<<16), f1=__uint_as_float(v.x&0xffff0000u);
    float f2=__uint_as_float(v.y<<16), f3=__uint_as_float(v.y&0xffff0000u);
    float f4=__uint_as_float(v.z<<16), f5=__uint_as_float(v.z&0xffff0000u);
    float f6=__uint_as_float(v.w<<16), f7=__uint_as_float(v.w&0xffff0000u);
    a[0]=fmaf(w,f0,a[0]); a[1]=fmaf(w,f1,a[1]); a[2]=fmaf(w,f2,a[2]); a[3]=fmaf(w,f3,a[3]);
    a[4]=fmaf(w,f4,a[4]); a[5]=fmaf(w,f5,a[5]); a[6]=fmaf(w,f6,a[6]); a[7]=fmaf(w,f7,a[7]);
}
__device__ __forceinline__ uint4 pack8(const float* a){
    uint4 r;
    r.x=((unsigned)f2bf(a[1])<<16)|f2bf(a[0]);
    r.y=((unsigned)f2bf(a[3])<<16)|f2bf(a[2]);
    r.z=((unsigned)f2bf(a[5])<<16)|f2bf(a[4]);
    r.w=((unsigned)f2bf(a[7])<<16)|f2bf(a[6]);
    return r;
}
__device__ __forceinline__ uint4 pack8s(const float* a, float s){
    uint4 r;
    r.x=((unsigned)f2bf(s*a[1])<<16)|f2bf(s*a[0]);
    r.y=((unsigned)f2bf(s*a[3])<<16)|f2bf(s*a[2]);
    r.z=((unsigned)f2bf(s*a[5])<<16)|f2bf(s*a[4]);
    r.w=((unsigned)f2bf(s*a[7])<<16)|f2bf(s*a[6]);
    return r;
}

// ---------------- init / graph ----------------

__global__ void k_zero(uint32_t* p, int n){
    int i = blockIdx.x*256 + threadIdx.x;
    if(i < n) p[i] = 0u;
}

__global__ void k_degree(const int* __restrict__ ei, int* degout, int* degin){
    int e = blockIdx.x*256 + threadIdx.x;
    if(e < NE){
        atomicAdd(&degout[ei[e]], 1);
        atomicAdd(&degin[ei[NE+e]], 1);
    }
}

__global__ void k_scan(const int* __restrict__ degin, int* __restrict__ coloff,
                       float* __restrict__ invdegin){
    __shared__ int part[1024];
    int t = threadIdx.x;
    int base = t*20;
    int s = 0;
    for(int k=0;k<20;k++){ int i = base+k; if(i < NN) s += degin[i]; }
    part[t] = s;
    __syncthreads();
    for(int off=1; off<1024; off<<=1){
        int v = (t>=off) ? part[t-off] : 0;
        __syncthreads();
        part[t] += v;
        __syncthreads();
    }
    int run = (t>0) ? part[t-1] : 0;
    for(int k=0;k<20;k++){
        int i = base+k;
        if(i < NN){
            int d = degin[i];
            coloff[i] = run;
            run += d;
            invdegin[i] = (d>0) ? (1.0f/(float)d) : 0.0f;
        }
    }
    if(t==1023) coloff[NN] = part[1023];
}

__global__ void k_csr(const int* __restrict__ ei, const int* __restrict__ degout,
                      const int* __restrict__ coloff, int* cnt, int2* __restrict__ ew){
    int e = blockIdx.x*256 + threadIdx.x;
    if(e < NE){
        int r = ei[e], c = ei[NE+e];
        int pos = coloff[c] + atomicAdd(&cnt[c], 1);
        int2 v; v.x = r; v.y = __float_as_int(1.0f/(float)degout[r]);
        ew[pos] = v;
    }
}

// ---------------- CNN embedding ----------------
// y1T layout: [node][pos 0..31][c 0..31] bf16, pos 31 zeroed (pad for stats)

__global__ void k_conv1(const float* __restrict__ x, const float* __restrict__ w1,
                        const float* __restrict__ b1, us* __restrict__ y1T){
    __shared__ float w[320];
    __shared__ float bb[32];
    int t = threadIdx.x;
    for(int i=t;i<320;i+=256) w[i] = w1[i];
    if(t < 32) bb[t] = b1[t];
    __syncthreads();
    int gid = blockIdx.x*256 + t;      // 2500 blocks * 256 = 640000 = 20000*32 exact
    int node = gid>>5, p = gid&31;
    us* yo = y1T + (size_t)node*1024 + p*32;
    if(p >= 31){
        uint4 z = {0,0,0,0};
        *(uint4*)yo = z; *(uint4*)(yo+8) = z;
        *(uint4*)(yo+16) = z; *(uint4*)(yo+24) = z;
        return;
    }
    const float* xr = x + node*100 + 3*p;
    float xv[10];
    #pragma unroll
    for(int k=0;k<10;k++) xv[k] = xr[k];
    float o[32];
    #pragma unroll
    for(int c=0;c<32;c++){
        float a = bb[c];
        #pragma unroll
        for(int k=0;k<10;k++) a = fmaf(w[c*10+k], xv[k], a);
        o[c] = fmaxf(a, 0.0f);
    }
    *(uint4*)yo      = pack8(o);
    *(uint4*)(yo+8)  = pack8(o+8);
    *(uint4*)(yo+16) = pack8(o+16);
    *(uint4*)(yo+24) = pack8(o+24);
}

// stats over y1T [n][pos][c]: channel = slot & 31
__global__ void k_chanstats_T(const us* __restrict__ y, float* __restrict__ sq){
    int tid = blockIdx.x*256 + threadIdx.x;     // 256 blocks
    int slot = tid & 1023;
    int c = slot & 31;
    int node0 = tid >> 10;                      // 64 stripes
    float s = 0.f, q = 0.f;
    for(int n=node0; n<NN; n+=64){
        float v = bf2f(y[(size_t)n*1024 + slot]);
        s += v; q = fmaf(v, v, q);
    }
    s += __shfl_xor(s, 32);
    q += __shfl_xor(q, 32);
    if((threadIdx.x & 63) < 32){
        atomicAdd(&sq[c], s);
        atomicAdd(&sq[32+c], q);
    }
}

template<int SLOTS, int PPC>
__global__ void k_chanstats_bf(const us* __restrict__ y, float* __restrict__ sq){
    int tid = blockIdx.x*blockDim.x + threadIdx.x;
    int slot = tid & (SLOTS-1);
    int node0 = tid / SLOTS;
    int nstride = (gridDim.x*blockDim.x) / SLOTS;
    int c = slot / PPC;
    float s = 0.f, q = 0.f;
    for(int n=node0; n<NN; n+=nstride){
        float v = bf2f(y[(size_t)n*SLOTS + slot]);
        s += v; q = fmaf(v, v, q);
    }
    #pragma unroll
    for(int m=PPC>>1; m>0; m>>=1){
        s += __shfl_xor(s, m);
        q += __shfl_xor(q, m);
    }
    if((threadIdx.x & (PPC-1)) == 0){
        atomicAdd(&sq[c], s);
        atomicAdd(&sq[32+c], q);
    }
}

__global__ void k_bnfin(const float* __restrict__ sq, const float* __restrict__ gamma,
                        const float* __restrict__ beta, float* __restrict__ scsh,
                        float inv_count){
    int c = threadIdx.x;
    if(c < 32){
        float m = sq[c]*inv_count;
        float v = sq[32+c]*inv_count - m*m;
        float sc = gamma[c]*rsqrtf(v + 1e-5f);
        scsh[c] = sc;
        scsh[32+c] = beta[c] - m*sc;
    }
}

// fold BN1 scale into conv2 weights: Bf[kk][c2][c] = sc1[c]*w2[c2][c][kk]
__global__ void k_wfold(const float* __restrict__ w2, const float* __restrict__ scsh1,
                        us* __restrict__ Bf){
    int idx = blockIdx.x*256 + threadIdx.x;    // 40 blocks, 10240
    if(idx >= 10240) return;
    int kk = idx >> 10, c2 = (idx >> 5) & 31, c = idx & 31;
    Bf[idx] = f2bf(scsh1[c] * w2[c2*320 + c*10 + kk]);
}

// biasc[c2] = b2[c2] + sum_{c,kk} sh1[c]*w2[c2][c][kk]
__global__ void k_wbias(const float* __restrict__ w2, const float* __restrict__ scsh1,
                        const float* __restrict__ b2, float* __restrict__ biasc){
    int t = threadIdx.x;                       // 256
    int c2 = t >> 3, part = t & 7;
    float s = 0.f;
    for(int i=part; i<320; i+=8)
        s += scsh1[32 + i/10] * w2[c2*320 + i];
    s += __shfl_xor(s,1); s += __shfl_xor(s,2); s += __shfl_xor(s,4);
    if(part == 0) biasc[c2] = b2[c2] + s;
}

// conv2 via 10 shifted MFMAs
__global__ void __launch_bounds__(256) k_conv2m(const us* __restrict__ y1T,
        const us* __restrict__ Bf, const float* __restrict__ biasc,
        us* __restrict__ Xpre){
    int t = threadIdx.x;
    int wv = t>>6, l = t&63;
    int l15 = l&15, g = l>>4;
    int r0 = blockIdx.x*64 + wv*16;
    int arow = r0 + l15;
    int an = arow>>3, ap = arow&7;
    const us* abase = y1T + (size_t)an*1024 + (3*ap)*32 + g*8;
    const us* bbase = Bf + (size_t)l15*32 + g*8;
    f32x4 acc0 = {}, acc1 = {};
    #pragma unroll
    for(int kk=0;kk<10;kk++){
        s16x8 af = *(const s16x8*)(abase + kk*32);
        s16x8 b0 = *(const s16x8*)(bbase + kk*1024);
        s16x8 b1 = *(const s16x8*)(bbase + kk*1024 + 512);
        acc0 = __builtin_amdgcn_mfma_f32_16x16x32_bf16(af, b0, acc0, 0, 0, 0);
        acc1 = __builtin_amdgcn_mfma_f32_16x16x32_bf16(af, b1, acc1, 0, 0, 0);
    }
    int base = r0 + g*4;
    int n = base>>3, p0 = base&7;
    #pragma unroll
    for(int nf=0;nf<2;nf++){
        int c2 = nf*16 + l15;
        float bb = biasc[c2];
        f32x4 a = nf ? acc1 : acc0;
        float v0 = fmaxf(a[0]+bb,0.f), v1 = fmaxf(a[1]+bb,0.f);
        float v2 = fmaxf(a[2]+bb,0.f), v3 = fmaxf(a[3]+bb,0.f);
        uint2 pk;
        pk.x = ((unsigned)f2bf(v1)<<16)|f2bf(v0);
        pk.y = ((unsigned)f2bf(v3)<<16)|f2bf(v2);
        *(uint2*)&Xpre[(size_t)n*256 + c2*8 + p0] = pk;
    }
}

// build XHp [node][512]: chunk g: half0 = BN2(X)[g*8..], half1 = h0[g*8..]
__global__ void __launch_bounds__(256) k_prep(const us* __restrict__ Xpre,
        const float* __restrict__ scsh, const float* __restrict__ h0,
        us* __restrict__ XHp){
    int node = blockIdx.x*4 + (threadIdx.x>>6);
    if(node >= NN) return;
    int lane = threadIdx.x & 63;
    int half = lane>>5, g = lane&31;
    uint4 o;
    if(half == 0){
        uint4 v = *(const uint4*)(Xpre + (size_t)node*256 + g*8);
        float sc = scsh[g], sh = scsh[32+g];
        float y[8];
        y[0]=fmaf(sc,__uint_as_float(v.x<<16),sh); y[1]=fmaf(sc,__uint_as_float(v.x&0xffff0000u),sh);
        y[2]=fmaf(sc,__uint_as_float(v.y<<16),sh); y[3]=fmaf(sc,__uint_as_float(v.y&0xffff0000u),sh);
        y[4]=fmaf(sc,__uint_as_float(v.z<<16),sh); y[5]=fmaf(sc,__uint_as_float(v.z&0xffff0000u),sh);
        y[6]=fmaf(sc,__uint_as_float(v.w<<16),sh); y[7]=fmaf(sc,__uint_as_float(v.w&0xffff0000u),sh);
        o = pack8(y);
    }else{
        float4 a = *(const float4*)(h0 + (size_t)node*256 + g*8);
        float4 b = *(const float4*)(h0 + (size_t)node*256 + g*8 + 4);
        float y[8] = {a.x,a.y,a.z,a.w,b.x,b.y,b.z,b.w};
        o = pack8(y);
    }
    *(uint4*)(XHp + (size_t)node*512 + (size_t)g*16 + half*8) = o;
}

// ---------------- effective weights (transposed bf16, coalesced via LDS) ----------------
// term: 0:W00+W10-W02-W12 1:W01 2:W11 3:2*W02 4:2*W12

__device__ __forceinline__ float weff_val(const float* W, int term, size_t base){
    const size_t S = 512*256;
    if(term==0)      return W[0*S+base] + W[3*S+base] - W[2*S+base] - W[5*S+base];
    else if(term==1) return W[1*S+base];
    else if(term==2) return W[4*S+base];
    else if(term==3) return 2.0f*W[2*S+base];
    else             return 2.0f*W[5*S+base];
}

// Wt[col][k=kb*256+rr]; 64x64 tiles, coalesced read (j contiguous) + write (rr contiguous)
template<int NCOL>
__global__ void __launch_bounds__(256) k_wefft(const float* __restrict__ Wa,
        const float* __restrict__ Wb, us* __restrict__ Wt){
    __shared__ float tile[64*65];
    int bx = blockIdx.x;                 // kb * (NCOL/64) * 4 blocks
    constexpr int CT = NCOL/64;
    int kb = bx / (CT*4);
    int rem = bx % (CT*4);
    int ct = rem >> 2, rt = rem & 3;
    int col0 = ct*64, rr0 = rt*64;
    const float* W = (col0 < 256) ? Wa : Wb;
    int jb = col0 & 255;
    int term = kb >> 1, half = kb & 1;
    int t = threadIdx.x;
    int j_l = t & 63, r4 = t >> 6;
    #pragma unroll
    for(int it=0; it<16; it++){
        int rr_l = it*4 + r4;
        int row = half*256 + rr0 + rr_l;
        size_t base = (size_t)row*256 + jb + j_l;
        tile[j_l*65 + rr_l] = weff_val(W, term, base);
    }
    __syncthreads();
    int rr_w = t & 63;
    #pragma unroll
    for(int it=0; it<16; it++){
        int col_l = it*4 + r4;
        Wt[(size_t)(col0+col_l)*2560 + kb*256 + rr0 + rr_w] = f2bf(tile[col_l*65 + rr_w]);
    }
}

// ---------------- propagation ----------------

__global__ void __launch_bounds__(256) k_prop1(const us* __restrict__ XHp,
        const int* __restrict__ coloff, const int2* __restrict__ ew,
        const float* __restrict__ invdeg, us* __restrict__ T1op, us* __restrict__ T1ip){
    int node = blockIdx.x*4 + (threadIdx.x>>6);
    if(node >= NN) return;
    int lane = threadIdx.x & 63;
    size_t lo = (size_t)(lane&31)*16 + (lane>>5)*8;
    int s = __builtin_amdgcn_readfirstlane(coloff[node]);
    int e = __builtin_amdgcn_readfirstlane(coloff[node+1]);
    float ao[8]={0,0,0,0,0,0,0,0}, ai[8]={0,0,0,0,0,0,0,0};
    int j = s;
    for(; j+7 < e; j += 8){
        int2 ed[8]; uint4 v[8];
        #pragma unroll
        for(int i=0;i<8;i++) ed[i] = ew[j+i];
        #pragma unroll
        for(int i=0;i<8;i++) v[i] = *(const uint4*)(XHp+(size_t)ed[i].x*512+lo);
        #pragma unroll
        for(int i=0;i<8;i++) upd8(v[i], __int_as_float(ed[i].y), ao, ai);
    }
    for(; j < e; j++){
        int2 ed = ew[j];
        uint4 v = *(const uint4*)(XHp+(size_t)ed.x*512+lo);
        upd8(v, __int_as_float(ed.y), ao, ai);
    }
    float wi = invdeg[node];
    *(uint4*)(T1op+(size_t)node*512+lo) = pack8(ao);
    *(uint4*)(T1ip+(size_t)node*512+lo) = pack8s(ai,wi);
}

__global__ void __launch_bounds__(256) k_prop2(const us* __restrict__ T1op,
        const us* __restrict__ T1ip,
        const int* __restrict__ coloff, const int2* __restrict__ ew,
        const float* __restrict__ invdeg, us* __restrict__ P2op, us* __restrict__ P2ip){
    int node = blockIdx.x*4 + (threadIdx.x>>6);
    if(node >= NN) return;
    int lane = threadIdx.x & 63;
    size_t lo = (size_t)(lane&31)*16 + (lane>>5)*8;
    int s = __builtin_amdgcn_readfirstlane(coloff[node]);
    int e = __builtin_amdgcn_readfirstlane(coloff[node+1]);
    float ao[8]={0,0,0,0,0,0,0,0}, ai[8]={0,0,0,0,0,0,0,0};
    int j = s;
    for(; j+3 < e; j += 4){
        int2 ed[4]; uint4 va[4], vb[4];
        #pragma unroll
        for(int i=0;i<4;i++) ed[i] = ew[j+i];
        #pragma unroll
        for(int i=0;i<4;i++){
            size_t o = (size_t)ed[i].x*512+lo;
            va[i] = *(const uint4*)(T1op+o);
            vb[i] = *(const uint4*)(T1ip+o);
        }
        #pragma unroll
        for(int i=0;i<4;i++){
            updw(va[i], __int_as_float(ed[i].y), ao);
            updw(vb[i], 1.0f, ai);
        }
    }
    for(; j < e; j++){
        int2 ed = ew[j];
        size_t o = (size_t)ed.x*512+lo;
        updw(*(const uint4*)(T1op+o), __int_as_float(ed.y), ao);
        updw(*(const uint4*)(T1ip+o), 1.0f, ai);
    }
    float wi = invdeg[node];
    *(uint4*)(P2op+(size_t)node*512+lo) = pack8(ao);
    *(uint4*)(P2ip+(size_t)node*512+lo) = pack8s(ai,wi);
}

// unified pair-prop: half0 lanes weighted (o), half1 lanes plain + invdeg scale (i)
__global__ void __launch_bounds__(256) k_propu(const us* __restrict__ Yin,
        const int* __restrict__ coloff, const int2* __restrict__ ew,
        const float* __restrict__ invdeg, us* __restrict__ Pout){
    int node = blockIdx.x*4 + (threadIdx.x>>6);
    if(node >= NN) return;
    int lane = threadIdx.x & 63;
    int half = lane>>5;
    size_t lo = (size_t)(lane&31)*16 + half*8;
    int s = __builtin_amdgcn_readfirstlane(coloff[node]);
    int e = __builtin_amdgcn_readfirstlane(coloff[node+1]);
    float a[8]={0,0,0,0,0,0,0,0};
    int j = s;
    for(; j+7 < e; j += 8){
        int2 ed[8]; uint4 v[8];
        #pragma unroll
        for(int i=0;i<8;i++) ed[i] = ew[j+i];
        #pragma unroll
        for(int i=0;i<8;i++) v[i] = *(const uint4*)(Yin+(size_t)ed[i].x*512+lo);
        #pragma unroll
        for(int i=0;i<8;i++) updw(v[i], half ? 1.0f : __int_as_float(ed[i].y), a);
    }
    for(; j < e; j++){
        int2 ed = ew[j];
        uint4 v = *(const uint4*)(Yin+(size_t)ed.x*512+lo);
        updw(v, half ? 1.0f : __int_as_float(ed.y), a);
    }
    float sc = half ? invdeg[node] : 1.0f;
    *(uint4*)(Pout+(size_t)node*512+lo) = pack8s(a,sc);
}

// ---------------- bf16 MFMA GEMM: LDS-free, direct global->VGPR fragments ----------------
// Block = 128 rows x (WN*32) cols, 4 waves 2x2; wave tile = 64 x (WN*16).
// A frag (16B) contiguous in [node][512] chunk layout; B frag contiguous in Wt[col][k].
// MODE0: WN=4 (N=512); MODE1: WN=2 (N=256). Grid 640, XCD-affinity mapping.

template<int MODE, int WN>
__global__ void __launch_bounds__(256) k_gemm(const us* __restrict__ XG,
        const us* __restrict__ RG, const us* __restrict__ Wt,
        const float* __restrict__ bias0, const float* __restrict__ bias1,
        const float* __restrict__ h0, const float* __restrict__ Zin,
        float* __restrict__ out0, us* __restrict__ out1){
    constexpr int BNT = WN*32;
    int t = threadIdx.x;
    int wv = t>>6, lane = t&63;
    int l15 = lane&15, kg = lane>>4;

    int bid = blockIdx.x;
    int xcd = bid & 7, sblk = bid >> 3;
    int cidx = sblk & 3, r = (sblk >> 2)*8 + xcd;
    if(r >= 157) return;
    int row0 = r*128 + (wv>>1)*64;
    int col0 = cidx*BNT + (wv&1)*(WN*16);

    int aoff[4];
    #pragma unroll
    for(int i=0;i<4;i++){
        int gr = row0 + i*16 + l15;
        gr = (gr < NN) ? gr : NN-1;
        aoff[i] = gr*512 + kg*16;
    }
    int boff[WN];
    #pragma unroll
    for(int n=0;n<WN;n++)
        boff[n] = (col0 + n*16 + l15)*2560 + kg*8;

    f32x4 acc[4][WN] = {};

    for(int kb=0; kb<10; ++kb){
        const us* Ap;
        if(MODE == 0){
            Ap = XG + (size_t)(kb >> 1) * SBUF + (size_t)(kb & 1) * 8;
        }else{
            if((kb & 1) == 0) Ap = XG + (size_t)(kb >> 1) * SBUF;
            else Ap = RG + (size_t)((kb + 1) >> 2) * SBUF + (size_t)(((kb + 1) >> 1) & 1) * 8;
        }
        const us* Bp = Wt + kb*256;
        #pragma unroll
        for(int kt=0; kt<256; kt+=32){
            s16x8 af[4], bf[WN];
            #pragma unroll
            for(int i=0;i<4;i++)
                af[i] = *(const s16x8*)(Ap + aoff[i] + kt*2);
            #pragma unroll
            for(int n=0;n<WN;n++)
                bf[n] = *(const s16x8*)(Bp + boff[n] + kt);
            #pragma unroll
            for(int mi=0;mi<4;mi++){
                #pragma unroll
                for(int ni=0;ni<WN;ni++){
                    acc[mi][ni] = __builtin_amdgcn_mfma_f32_16x16x32_bf16(
                        af[mi], bf[ni], acc[mi][ni], 0, 0, 0);
                }
            }
        }
    }

    #pragma unroll
    for(int mi=0;mi<4;mi++){
        int gr0 = row0 + mi*16 + kg*4;
        #pragma unroll
        for(int ni=0;ni<WN;ni++){
            int j = col0 + ni*16 + l15;
            #pragma unroll
            for(int rr=0;rr<4;rr++){
                int gr = gr0 + rr;
                if(gr < NN){
                    float a = acc[mi][ni][rr];
                    if(MODE == 0){
                        if(j < 256){
                            out0[(size_t)gr*256 + j] = 1.0f/(1.0f + expf(-(a + bias0[j])));
                        }else{
                            int jj = j - 256;
                            float rv = 1.0f/(1.0f + expf(-(a + bias1[jj])));
                            us v = f2bf(rv * h0[(size_t)gr*256 + jj]);
                            size_t base = (size_t)gr*512 + (size_t)(jj>>3)*16 + (jj&7);
                            out1[base] = v;
                            out1[base+8] = v;
                        }
                    }else{
                        float z = Zin[(size_t)gr*256 + j];
                        float ht = tanhf(a + bias0[j]);
                        float H = z*h0[(size_t)gr*256 + j] + (1.0f - z)*ht;
                        out0[(size_t)gr*256 + j] = fmaxf(H, 0.0f);
                    }
                }
            }
        }
    }
}

// ---------------- host ----------------

extern "C" void kernel_launch(void* const* d_in, const int* in_sizes, int n_in,
                              void* d_out, int out_size, void* d_ws, size_t ws_size,
                              hipStream_t stream){
    const float* x   = (const float*)d_in[0];
    const int*   ei  = (const int*)  d_in[1];
    const float* h0  = (const float*)d_in[2];
    const float* w1  = (const float*)d_in[3];
    const float* b1  = (const float*)d_in[4];
    const float* g1  = (const float*)d_in[5];
    const float* be1 = (const float*)d_in[6];
    const float* w2  = (const float*)d_in[7];
    const float* b2  = (const float*)d_in[8];
    const float* g2  = (const float*)d_in[9];
    const float* be2 = (const float*)d_in[10];
    const float* Wz  = (const float*)d_in[11];
    const float* bz  = (const float*)d_in[12];
    const float* Wr  = (const float*)d_in[13];
    const float* br  = (const float*)d_in[14];
    const float* Wh  = (const float*)d_in[15];
    const float* bh  = (const float*)d_in[16];
    float* out = (float*)d_out;
    float* wsf = (float*)d_ws;
    (void)in_sizes; (void)n_in; (void)out_size;

    // word (4B) offsets
    const size_t O_DEGO=0, O_DEGI=20000, O_CNT=40000, O_BN=60000;      // zero: 60256
    const size_t O_COLOFF=60288, O_EW=80384, O_INVDEG=720384;
    const size_t O_WTZR=740480, O_WTH=1395840;
    const size_t O_XPRE=1723520;
    const size_t O_XG=4283520;                 // 5 bufs x 5,120,000 words
    const size_t O_RG=29883520;                // 3 bufs x 5,120,000 words
    const size_t O_Z=45243520;                 // 20000x256 f32
    const size_t O_BF=50363520;                // conv2 folded weights, 2560 words
    const size_t WS_NEED_BYTES = (size_t)50366080 * 4;   // ~201.5 MB (236 MB proven)
    if(ws_size < WS_NEED_BYTES) return;

    const size_t SW = 5120000;

    int* degout = (int*)(wsf + O_DEGO);
    int* degin  = (int*)(wsf + O_DEGI);
    int* cnt    = (int*)(wsf + O_CNT);
    float* bn   = wsf + O_BN;          // [0:64)s1 [64:128)scsh1 [128:192)s2 [192:256)scsh2 [256:288)biasc
    int* coloff = (int*)(wsf + O_COLOFF);
    int2* ew    = (int2*)(wsf + O_EW);
    float* invdeg = wsf + O_INVDEG;
    us* Wtzr = (us*)(wsf + O_WTZR);
    us* Wth  = (us*)(wsf + O_WTH);
    us* Xpre = (us*)(wsf + O_XPRE);
    us* XG   = (us*)(wsf + O_XG);
    us* RG   = (us*)(wsf + O_RG);
    us* XHp  = XG;
    us* T1op = (us*)(wsf + O_XG + SW);
    us* T1ip = (us*)(wsf + O_XG + 2*SW);
    us* P2op = (us*)(wsf + O_XG + 3*SW);
    us* P2ip = (us*)(wsf + O_XG + 4*SW);
    us* RHp  = RG;
    us* Q1p  = (us*)(wsf + O_RG + SW);
    us* Q2p  = (us*)(wsf + O_RG + 2*SW);
    float* Z = wsf + O_Z;
    us* Bf   = (us*)(wsf + O_BF);
    us* y1T  = T1op;   // dead during CNN

    // graph CSR
    k_zero<<<236,256,0,stream>>>((uint32_t*)(wsf + O_DEGO), 60256);
    k_degree<<<1250,256,0,stream>>>(ei, degout, degin);
    k_scan<<<1,1024,0,stream>>>(degin, coloff, invdeg);
    k_csr<<<1250,256,0,stream>>>(ei, degout, coloff, cnt, ew);

    // CNN embedding
    k_conv1<<<2500,256,0,stream>>>(x, w1, b1, y1T);
    k_chanstats_T<<<256,256,0,stream>>>(y1T, bn+0);
    k_bnfin<<<1,32,0,stream>>>(bn+0, g1, be1, bn+64, 1.0f/620000.0f);
    k_wfold<<<40,256,0,stream>>>(w2, bn+64, Bf);
    k_wbias<<<1,256,0,stream>>>(w2, bn+64, b2, bn+256);
    k_conv2m<<<2500,256,0,stream>>>(y1T, Bf, bn+256, Xpre);
    k_chanstats_bf<256,8><<<64,256,0,stream>>>(Xpre, bn+128);
    k_bnfin<<<1,32,0,stream>>>(bn+128, g2, be2, bn+192, 1.0f/160000.0f);
    k_prep<<<5000,256,0,stream>>>(Xpre, bn+192, h0, XHp);

    // effective weights (transposed bf16, coalesced)
    k_wefft<512><<<320,256,0,stream>>>(Wz, Wr, Wtzr);
    k_wefft<256><<<160,256,0,stream>>>(Wh, Wh, Wth);

    // hop1 + hop2 props
    k_prop1<<<5000,256,0,stream>>>(XHp, coloff, ew, invdeg, T1op, T1ip);
    k_prop2<<<5000,256,0,stream>>>(T1op, T1ip, coloff, ew, invdeg, P2op, P2ip);

    // Z,R GEMM (fused sigmoid; RHp = bf16(sigmoid(r)*h0), duplicated halves)
    k_gemm<0,4><<<640,256,0,stream>>>(XG, RG, Wtzr, bz, br, h0, nullptr, Z, RHp);

    // props of RH
    k_propu<<<5000,256,0,stream>>>(RHp, coloff, ew, invdeg, Q1p);
    k_propu<<<5000,256,0,stream>>>(Q1p, coloff, ew, invdeg, Q2p);

    // H~ GEMM (fused tanh + gate + relu -> out)
    k_gemm<1,2><<<640,256,0,stream>>>(XG, RG, Wth, bh, nullptr, h0, Z, out, nullptr);
}

// Round 11
// 787.304 us; speedup vs baseline: 1.2693x; 1.2693x over previous
//
#include <hip/hip_runtime.h>
#include <cstdint>
#include <cstddef>

#define NN 20000
#define NE 320000
#define SBUF 10240000   // shorts per [node][512] buffer

typedef float f32x4 __attribute__((ext_vector_type(4)));
typedef short s16x8 __attribute__((ext_vector_type(8)));
typedef unsigned short us;

__device__ __forceinline__ us f2bf(float x){
    unsigned u = __float_as_uint(x);
    unsigned r = (u + 0x7fffu + ((u >> 16) & 1u)) >> 16;
    return (us)r;
}
__device__ __forceinline__ float bf2f(us s){
    return __uint_as_float(((unsigned)s) << 16);
}

__device__ __forceinline__ void gl16(const void* g, void* l){
    __builtin_amdgcn_global_load_lds((const __attribute__((address_space(1))) unsigned int*)g,
                                     (__attribute__((address_space(3))) unsigned int*)l, 16, 0, 0);
}

__device__ __forceinline__ void upd8(uint4 v, float w, float* ao, float* ai){
    float f0=__uint_as_float(v.x<<16), f1=__uint_as_float(v.x&0xffff0000u);
    float f2=__uint_as_float(v.y<<16), f3=__uint_as_float(v.y&0xffff0000u);
    float f4=__uint_as_float(v.z<<16), f5=__uint_as_float(v.z&0xffff0000u);
    float f6=__uint_as_float(v.w<<16), f7=__uint_as_float(v.w&0xffff0000u);
    ao[0]=fmaf(w,f0,ao[0]); ao[1]=fmaf(w,f1,ao[1]); ao[2]=fmaf(w,f2,ao[2]); ao[3]=fmaf(w,f3,ao[3]);
    ao[4]=fmaf(w,f4,ao[4]); ao[5]=fmaf(w,f5,ao[5]); ao[6]=fmaf(w,f6,ao[6]); ao[7]=fmaf(w,f7,ao[7]);
    ai[0]+=f0; ai[1]+=f1; ai[2]+=f2; ai[3]+=f3; ai[4]+=f4; ai[5]+=f5; ai[6]+=f6; ai[7]+=f7;
}
__device__ __forceinline__ void updw(uint4 v, float w, float* a){
    float f0=__uint_as_float(v.x<<16), f1=__uint_as_float(v.x&0xffff0000u);
    float f2=__uint_as_float(v.y<<16), f3=__uint_as_float(v.y&0xffff0000u);
    float f4=__uint_as_float(v.z<<16), f5=__uint_as_float(v.z&0xffff0000u);
    float f6=__uint_as_float(v.w<<16), f7=__uint_as_float(v.w&0xffff0000u);
    a[0]=fmaf(w,f0,a[0]); a[1]=fmaf(w,f1,a[1]); a[2]=fmaf(w,f2,a[2]); a[3]=fmaf(w,f3,a[3]);
    a[4]=fmaf(w,f4,a[4]); a[5]=fmaf(w,f5,a[5]); a[6]=fmaf(w,f6,a[6]); a[7]=fmaf(w,f7,a[7]);
}
__device__ __forceinline__ uint4 pack8(const float* a){
    uint4 r;
    r.x=((unsigned)f2bf(a[1])<<16)|f2bf(a[0]);
    r.y=((unsigned)f2bf(a[3])<<16)|f2bf(a[2]);
    r.z=((unsigned)f2bf(a[5])<<16)|f2bf(a[4]);
    r.w=((unsigned)f2bf(a[7])<<16)|f2bf(a[6]);
    return r;
}
__device__ __forceinline__ uint4 pack8s(const float* a, float s){
    uint4 r;
    r.x=((unsigned)f2bf(s*a[1])<<16)|f2bf(s*a[0]);
    r.y=((unsigned)f2bf(s*a[3])<<16)|f2bf(s*a[2]);
    r.z=((unsigned)f2bf(s*a[5])<<16)|f2bf(s*a[4]);
    r.w=((unsigned)f2bf(s*a[7])<<16)|f2bf(s*a[6]);
    return r;
}

// ---------------- init / graph ----------------

__global__ void k_zero(uint32_t* p, int n){
    int i = blockIdx.x*256 + threadIdx.x;
    if(i < n) p[i] = 0u;
}

__global__ void k_degree(const int* __restrict__ ei, int* degout, int* degin){
    int e = blockIdx.x*256 + threadIdx.x;
    if(e < NE){
        atomicAdd(&degout[ei[e]], 1);
        atomicAdd(&degin[ei[NE+e]], 1);
    }
}

__global__ void k_scan(const int* __restrict__ degin, int* __restrict__ coloff,
                       float* __restrict__ invdegin){
    __shared__ int part[1024];
    int t = threadIdx.x;
    int base = t*20;
    int s = 0;
    for(int k=0;k<20;k++){ int i = base+k; if(i < NN) s += degin[i]; }
    part[t] = s;
    __syncthreads();
    for(int off=1; off<1024; off<<=1){
        int v = (t>=off) ? part[t-off] : 0;
        __syncthreads();
        part[t] += v;
        __syncthreads();
    }
    int run = (t>0) ? part[t-1] : 0;
    for(int k=0;k<20;k++){
        int i = base+k;
        if(i < NN){
            int d = degin[i];
            coloff[i] = run;
            run += d;
            invdegin[i] = (d>0) ? (1.0f/(float)d) : 0.0f;
        }
    }
    if(t==1023) coloff[NN] = part[1023];
}

__global__ void k_csr(const int* __restrict__ ei, const int* __restrict__ degout,
                      const int* __restrict__ coloff, int* cnt, int2* __restrict__ ew){
    int e = blockIdx.x*256 + threadIdx.x;
    if(e < NE){
        int r = ei[e], c = ei[NE+e];
        int pos = coloff[c] + atomicAdd(&cnt[c], 1);
        int2 v; v.x = r; v.y = __float_as_int(1.0f/(float)degout[r]);
        ew[pos] = v;
    }
}

// ---------------- CNN embedding ----------------
// y1T layout: [node][pos 0..31][c 0..31] bf16, pos 31 zeroed (pad for stats)

__global__ void k_conv1(const float* __restrict__ x, const float* __restrict__ w1,
                        const float* __restrict__ b1, us* __restrict__ y1T){
    __shared__ float w[320];
    __shared__ float bb[32];
    int t = threadIdx.x;
    for(int i=t;i<320;i+=256) w[i] = w1[i];
    if(t < 32) bb[t] = b1[t];
    __syncthreads();
    int gid = blockIdx.x*256 + t;      // 2500 blocks * 256 = 640000 = 20000*32 exact
    int node = gid>>5, p = gid&31;
    us* yo = y1T + (size_t)node*1024 + p*32;
    if(p >= 31){
        uint4 z = {0,0,0,0};
        *(uint4*)yo = z; *(uint4*)(yo+8) = z;
        *(uint4*)(yo+16) = z; *(uint4*)(yo+24) = z;
        return;
    }
    const float* xr = x + node*100 + 3*p;
    float xv[10];
    #pragma unroll
    for(int k=0;k<10;k++) xv[k] = xr[k];
    float o[32];
    #pragma unroll
    for(int c=0;c<32;c++){
        float a = bb[c];
        #pragma unroll
        for(int k=0;k<10;k++) a = fmaf(w[c*10+k], xv[k], a);
        o[c] = fmaxf(a, 0.0f);
    }
    *(uint4*)yo      = pack8(o);
    *(uint4*)(yo+8)  = pack8(o+8);
    *(uint4*)(yo+16) = pack8(o+16);
    *(uint4*)(yo+24) = pack8(o+24);
}

// stats over y1T [n][pos][c]: channel = slot & 31
__global__ void k_chanstats_T(const us* __restrict__ y, float* __restrict__ sq){
    int tid = blockIdx.x*256 + threadIdx.x;     // 256 blocks
    int slot = tid & 1023;
    int c = slot & 31;
    int node0 = tid >> 10;                      // 64 stripes
    float s = 0.f, q = 0.f;
    for(int n=node0; n<NN; n+=64){
        float v = bf2f(y[(size_t)n*1024 + slot]);
        s += v; q = fmaf(v, v, q);
    }
    s += __shfl_xor(s, 32);
    q += __shfl_xor(q, 32);
    if((threadIdx.x & 63) < 32){
        atomicAdd(&sq[c], s);
        atomicAdd(&sq[32+c], q);
    }
}

template<int SLOTS, int PPC>
__global__ void k_chanstats_bf(const us* __restrict__ y, float* __restrict__ sq){
    int tid = blockIdx.x*blockDim.x + threadIdx.x;
    int slot = tid & (SLOTS-1);
    int node0 = tid / SLOTS;
    int nstride = (gridDim.x*blockDim.x) / SLOTS;
    int c = slot / PPC;
    float s = 0.f, q = 0.f;
    for(int n=node0; n<NN; n+=nstride){
        float v = bf2f(y[(size_t)n*SLOTS + slot]);
        s += v; q = fmaf(v, v, q);
    }
    #pragma unroll
    for(int m=PPC>>1; m>0; m>>=1){
        s += __shfl_xor(s, m);
        q += __shfl_xor(q, m);
    }
    if((threadIdx.x & (PPC-1)) == 0){
        atomicAdd(&sq[c], s);
        atomicAdd(&sq[32+c], q);
    }
}

__global__ void k_bnfin(const float* __restrict__ sq, const float* __restrict__ gamma,
                        const float* __restrict__ beta, float* __restrict__ scsh,
                        float inv_count){
    int c = threadIdx.x;
    if(c < 32){
        float m = sq[c]*inv_count;
        float v = sq[32+c]*inv_count - m*m;
        float sc = gamma[c]*rsqrtf(v + 1e-5f);
        scsh[c] = sc;
        scsh[32+c] = beta[c] - m*sc;
    }
}

// fold BN1 scale into conv2 weights: Bf[kk][c2][c] = sc1[c]*w2[c2][c][kk]
__global__ void k_wfold(const float* __restrict__ w2, const float* __restrict__ scsh1,
                        us* __restrict__ Bf){
    int idx = blockIdx.x*256 + threadIdx.x;    // 40 blocks, 10240
    if(idx >= 10240) return;
    int kk = idx >> 10, c2 = (idx >> 5) & 31, c = idx & 31;
    Bf[idx] = f2bf(scsh1[c] * w2[c2*320 + c*10 + kk]);
}

// biasc[c2] = b2[c2] + sum_{c,kk} sh1[c]*w2[c2][c][kk]
__global__ void k_wbias(const float* __restrict__ w2, const float* __restrict__ scsh1,
                        const float* __restrict__ b2, float* __restrict__ biasc){
    int t = threadIdx.x;                       // 256
    int c2 = t >> 3, part = t & 7;
    float s = 0.f;
    for(int i=part; i<320; i+=8)
        s += scsh1[32 + i/10] * w2[c2*320 + i];
    s += __shfl_xor(s,1); s += __shfl_xor(s,2); s += __shfl_xor(s,4);
    if(part == 0) biasc[c2] = b2[c2] + s;
}

// conv2 via 10 shifted MFMAs
__global__ void __launch_bounds__(256) k_conv2m(const us* __restrict__ y1T,
        const us* __restrict__ Bf, const float* __restrict__ biasc,
        us* __restrict__ Xpre){
    int t = threadIdx.x;
    int wv = t>>6, l = t&63;
    int l15 = l&15, g = l>>4;
    int r0 = blockIdx.x*64 + wv*16;
    int arow = r0 + l15;
    int an = arow>>3, ap = arow&7;
    const us* abase = y1T + (size_t)an*1024 + (3*ap)*32 + g*8;
    const us* bbase = Bf + (size_t)l15*32 + g*8;
    f32x4 acc0 = {}, acc1 = {};
    #pragma unroll
    for(int kk=0;kk<10;kk++){
        s16x8 af = *(const s16x8*)(abase + kk*32);
        s16x8 b0 = *(const s16x8*)(bbase + kk*1024);
        s16x8 b1 = *(const s16x8*)(bbase + kk*1024 + 512);
        acc0 = __builtin_amdgcn_mfma_f32_16x16x32_bf16(af, b0, acc0, 0, 0, 0);
        acc1 = __builtin_amdgcn_mfma_f32_16x16x32_bf16(af, b1, acc1, 0, 0, 0);
    }
    int base = r0 + g*4;
    int n = base>>3, p0 = base&7;
    #pragma unroll
    for(int nf=0;nf<2;nf++){
        int c2 = nf*16 + l15;
        float bb = biasc[c2];
        f32x4 a = nf ? acc1 : acc0;
        float v0 = fmaxf(a[0]+bb,0.f), v1 = fmaxf(a[1]+bb,0.f);
        float v2 = fmaxf(a[2]+bb,0.f), v3 = fmaxf(a[3]+bb,0.f);
        uint2 pk;
        pk.x = ((unsigned)f2bf(v1)<<16)|f2bf(v0);
        pk.y = ((unsigned)f2bf(v3)<<16)|f2bf(v2);
        *(uint2*)&Xpre[(size_t)n*256 + c2*8 + p0] = pk;
    }
}

// build XHp [node][512]: chunk g: half0 = BN2(X)[g*8..], half1 = h0[g*8..]
__global__ void __launch_bounds__(256) k_prep(const us* __restrict__ Xpre,
        const float* __restrict__ scsh, const float* __restrict__ h0,
        us* __restrict__ XHp){
    int node = blockIdx.x*4 + (threadIdx.x>>6);
    if(node >= NN) return;
    int lane = threadIdx.x & 63;
    int half = lane>>5, g = lane&31;
    uint4 o;
    if(half == 0){
        uint4 v = *(const uint4*)(Xpre + (size_t)node*256 + g*8);
        float sc = scsh[g], sh = scsh[32+g];
        float y[8];
        y[0]=fmaf(sc,__uint_as_float(v.x<<16),sh); y[1]=fmaf(sc,__uint_as_float(v.x&0xffff0000u),sh);
        y[2]=fmaf(sc,__uint_as_float(v.y<<16),sh); y[3]=fmaf(sc,__uint_as_float(v.y&0xffff0000u),sh);
        y[4]=fmaf(sc,__uint_as_float(v.z<<16),sh); y[5]=fmaf(sc,__uint_as_float(v.z&0xffff0000u),sh);
        y[6]=fmaf(sc,__uint_as_float(v.w<<16),sh); y[7]=fmaf(sc,__uint_as_float(v.w&0xffff0000u),sh);
        o = pack8(y);
    }else{
        float4 a = *(const float4*)(h0 + (size_t)node*256 + g*8);
        float4 b = *(const float4*)(h0 + (size_t)node*256 + g*8 + 4);
        float y[8] = {a.x,a.y,a.z,a.w,b.x,b.y,b.z,b.w};
        o = pack8(y);
    }
    *(uint4*)(XHp + (size_t)node*512 + (size_t)g*16 + half*8) = o;
}

// ---------------- effective weights (transposed bf16, coalesced via LDS) ----------------
// term: 0:W00+W10-W02-W12 1:W01 2:W11 3:2*W02 4:2*W12

__device__ __forceinline__ float weff_val(const float* W, int term, size_t base){
    const size_t S = 512*256;
    if(term==0)      return W[0*S+base] + W[3*S+base] - W[2*S+base] - W[5*S+base];
    else if(term==1) return W[1*S+base];
    else if(term==2) return W[4*S+base];
    else if(term==3) return 2.0f*W[2*S+base];
    else             return 2.0f*W[5*S+base];
}

// Wt[col][k=kb*256+rr]; 64x64 tiles, coalesced read (j contiguous) + write (rr contiguous)
template<int NCOL>
__global__ void __launch_bounds__(256) k_wefft(const float* __restrict__ Wa,
        const float* __restrict__ Wb, us* __restrict__ Wt){
    __shared__ float tile[64*65];
    int bx = blockIdx.x;                 // kb * (NCOL/64) * 4 blocks
    constexpr int CT = NCOL/64;
    int kb = bx / (CT*4);
    int rem = bx % (CT*4);
    int ct = rem >> 2, rt = rem & 3;
    int col0 = ct*64, rr0 = rt*64;
    const float* W = (col0 < 256) ? Wa : Wb;
    int jb = col0 & 255;
    int term = kb >> 1, half = kb & 1;
    int t = threadIdx.x;
    int j_l = t & 63, r4 = t >> 6;
    #pragma unroll
    for(int it=0; it<16; it++){
        int rr_l = it*4 + r4;
        int row = half*256 + rr0 + rr_l;
        size_t base = (size_t)row*256 + jb + j_l;
        tile[j_l*65 + rr_l] = weff_val(W, term, base);
    }
    __syncthreads();
    int rr_w = t & 63;
    #pragma unroll
    for(int it=0; it<16; it++){
        int col_l = it*4 + r4;
        Wt[(size_t)(col0+col_l)*2560 + kb*256 + rr0 + rr_w] = f2bf(tile[col_l*65 + rr_w]);
    }
}

// ---------------- propagation ----------------

__global__ void __launch_bounds__(256) k_prop1(const us* __restrict__ XHp,
        const int* __restrict__ coloff, const int2* __restrict__ ew,
        const float* __restrict__ invdeg, us* __restrict__ T1op, us* __restrict__ T1ip){
    int node = blockIdx.x*4 + (threadIdx.x>>6);
    if(node >= NN) return;
    int lane = threadIdx.x & 63;
    size_t lo = (size_t)(lane&31)*16 + (lane>>5)*8;
    int s = __builtin_amdgcn_readfirstlane(coloff[node]);
    int e = __builtin_amdgcn_readfirstlane(coloff[node+1]);
    float ao[8]={0,0,0,0,0,0,0,0}, ai[8]={0,0,0,0,0,0,0,0};
    int j = s;
    for(; j+7 < e; j += 8){
        int2 ed[8]; uint4 v[8];
        #pragma unroll
        for(int i=0;i<8;i++) ed[i] = ew[j+i];
        #pragma unroll
        for(int i=0;i<8;i++) v[i] = *(const uint4*)(XHp+(size_t)ed[i].x*512+lo);
        #pragma unroll
        for(int i=0;i<8;i++) upd8(v[i], __int_as_float(ed[i].y), ao, ai);
    }
    for(; j < e; j++){
        int2 ed = ew[j];
        uint4 v = *(const uint4*)(XHp+(size_t)ed.x*512+lo);
        upd8(v, __int_as_float(ed.y), ao, ai);
    }
    float wi = invdeg[node];
    *(uint4*)(T1op+(size_t)node*512+lo) = pack8(ao);
    *(uint4*)(T1ip+(size_t)node*512+lo) = pack8s(ai,wi);
}

__global__ void __launch_bounds__(256) k_prop2(const us* __restrict__ T1op,
        const us* __restrict__ T1ip,
        const int* __restrict__ coloff, const int2* __restrict__ ew,
        const float* __restrict__ invdeg, us* __restrict__ P2op, us* __restrict__ P2ip){
    int node = blockIdx.x*4 + (threadIdx.x>>6);
    if(node >= NN) return;
    int lane = threadIdx.x & 63;
    size_t lo = (size_t)(lane&31)*16 + (lane>>5)*8;
    int s = __builtin_amdgcn_readfirstlane(coloff[node]);
    int e = __builtin_amdgcn_readfirstlane(coloff[node+1]);
    float ao[8]={0,0,0,0,0,0,0,0}, ai[8]={0,0,0,0,0,0,0,0};
    int j = s;
    for(; j+3 < e; j += 4){
        int2 ed[4]; uint4 va[4], vb[4];
        #pragma unroll
        for(int i=0;i<4;i++) ed[i] = ew[j+i];
        #pragma unroll
        for(int i=0;i<4;i++){
            size_t o = (size_t)ed[i].x*512+lo;
            va[i] = *(const uint4*)(T1op+o);
            vb[i] = *(const uint4*)(T1ip+o);
        }
        #pragma unroll
        for(int i=0;i<4;i++){
            updw(va[i], __int_as_float(ed[i].y), ao);
            updw(vb[i], 1.0f, ai);
        }
    }
    for(; j < e; j++){
        int2 ed = ew[j];
        size_t o = (size_t)ed.x*512+lo;
        updw(*(const uint4*)(T1op+o), __int_as_float(ed.y), ao);
        updw(*(const uint4*)(T1ip+o), 1.0f, ai);
    }
    float wi = invdeg[node];
    *(uint4*)(P2op+(size_t)node*512+lo) = pack8(ao);
    *(uint4*)(P2ip+(size_t)node*512+lo) = pack8s(ai,wi);
}

// unified pair-prop: half0 lanes weighted (o), half1 lanes plain + invdeg scale (i)
__global__ void __launch_bounds__(256) k_propu(const us* __restrict__ Yin,
        const int* __restrict__ coloff, const int2* __restrict__ ew,
        const float* __restrict__ invdeg, us* __restrict__ Pout){
    int node = blockIdx.x*4 + (threadIdx.x>>6);
    if(node >= NN) return;
    int lane = threadIdx.x & 63;
    int half = lane>>5;
    size_t lo = (size_t)(lane&31)*16 + half*8;
    int s = __builtin_amdgcn_readfirstlane(coloff[node]);
    int e = __builtin_amdgcn_readfirstlane(coloff[node+1]);
    float a[8]={0,0,0,0,0,0,0,0};
    int j = s;
    for(; j+7 < e; j += 8){
        int2 ed[8]; uint4 v[8];
        #pragma unroll
        for(int i=0;i<8;i++) ed[i] = ew[j+i];
        #pragma unroll
        for(int i=0;i<8;i++) v[i] = *(const uint4*)(Yin+(size_t)ed[i].x*512+lo);
        #pragma unroll
        for(int i=0;i<8;i++) updw(v[i], half ? 1.0f : __int_as_float(ed[i].y), a);
    }
    for(; j < e; j++){
        int2 ed = ew[j];
        uint4 v = *(const uint4*)(Yin+(size_t)ed.x*512+lo);
        updw(v, half ? 1.0f : __int_as_float(ed.y), a);
    }
    float sc = half ? invdeg[node] : 1.0f;
    *(uint4*)(Pout+(size_t)node*512+lo) = pack8s(a,sc);
}

// ---------------- bf16 MFMA GEMM: 4-buffer, depth-3 prefetch, counted-vmcnt ----------------
// Per iter s: vmcnt(2L) [drains stage s; s+1,s+2 remain] -> barrier -> issue stage(s+3)
// (targets buf (s-1)&3, safe: its readers finished before barrier) -> ds_read buf s&3 -> MFMA.

template<int MODE, int BNT>
__global__ void __launch_bounds__(256) k_gemm(const us* __restrict__ XG,
        const us* __restrict__ RG, const us* __restrict__ Wt,
        const float* __restrict__ bias0, const float* __restrict__ bias1,
        const float* __restrict__ h0, const float* __restrict__ Zin,
        float* __restrict__ out0, us* __restrict__ out1){
    constexpr int WN = BNT/32;
    constexpr int NB = BNT/64;          // B gl16 per thread per step
    __shared__ us As[4][4096];
    __shared__ us Bs[4][BNT*32];
    int t = threadIdx.x;
    int wid = t >> 6, lane = t & 63;
    int l15 = lane & 15, kg = lane >> 4;

    int bid = blockIdx.x;
    int xcd = bid & 7, sblk = bid >> 3;
    int cidx = sblk & 3, r = (sblk >> 2)*8 + xcd;
    if(r >= 157) return;
    int row0 = r*128, col0 = cidx*BNT;
    int rowbase = (wid >> 1)*64, colbase = (wid & 1)*(BNT/2);
    int swz = (l15 >> 1) & 3;

    int srA[2], sgA[2];
    size_t rowoffA[2];
    #pragma unroll
    for(int i=0;i<2;i++){
        int c = t + i*256;
        srA[i] = c >> 2;
        sgA[i] = (c & 3) ^ ((srA[i] >> 1) & 3);
        int gr = row0 + srA[i];
        gr = (gr < NN) ? gr : NN-1;
        rowoffA[i] = (size_t)gr*512 + (size_t)sgA[i]*16;
    }
    int srB[NB], sgB[NB];
    size_t coloffB[NB];
    #pragma unroll
    for(int i=0;i<NB;i++){
        int c = t + i*256;
        srB[i] = c >> 2;
        sgB[i] = (c & 3) ^ ((srB[i] >> 1) & 3);
        coloffB[i] = (size_t)(col0+srB[i])*2560 + (size_t)sgB[i]*8;
    }

    f32x4 acc[4][WN] = {};

    auto stage = [&](int buf, int s){
        int kb = s >> 3;
        int ktc = (s & 7) * 4;
        const us* Ap;
        if(MODE == 0){
            Ap = XG + (size_t)(kb >> 1) * SBUF + (size_t)(kb & 1) * 8;
        }else{
            if((kb & 1) == 0) Ap = XG + (size_t)(kb >> 1) * SBUF;
            else Ap = RG + (size_t)((kb + 1) >> 2) * SBUF + (size_t)(((kb + 1) >> 1) & 1) * 8;
        }
        #pragma unroll
        for(int i=0;i<2;i++)
            gl16(Ap + rowoffA[i] + (size_t)ktc*16, &As[buf][(t+i*256)*8]);
        const us* Wp = Wt + (size_t)kb*256 + (s & 7)*32;
        #pragma unroll
        for(int i=0;i<NB;i++)
            gl16(Wp + coloffB[i], &Bs[buf][(t+i*256)*8]);
    };

    stage(0, 0);
    stage(1, 1);
    stage(2, 2);
    for(int step=0; step<80; ++step){
        int cur = step & 3;
        if(step < 78){
            if(MODE == 0) asm volatile("s_waitcnt vmcnt(8)" ::: "memory");
            else          asm volatile("s_waitcnt vmcnt(6)" ::: "memory");
        }else if(step == 78){
            if(MODE == 0) asm volatile("s_waitcnt vmcnt(4)" ::: "memory");
            else          asm volatile("s_waitcnt vmcnt(3)" ::: "memory");
        }else{
            asm volatile("s_waitcnt vmcnt(0)" ::: "memory");
        }
        __builtin_amdgcn_s_barrier();
        __builtin_amdgcn_sched_barrier(0);
        if(step < 77) stage((step+3) & 3, step+3);
        s16x8 af[4], bfr[WN];
        #pragma unroll
        for(int i=0;i<4;i++){
            int row = rowbase + i*16 + l15;
            af[i] = *(const s16x8*)&As[cur][(row*4 + (kg ^ swz))*8];
        }
        #pragma unroll
        for(int n=0;n<WN;n++){
            int colr = colbase + n*16 + l15;
            bfr[n] = *(const s16x8*)&Bs[cur][(colr*4 + (kg ^ swz))*8];
        }
        __builtin_amdgcn_s_setprio(1);
        #pragma unroll
        for(int mi=0;mi<4;mi++){
            #pragma unroll
            for(int ni=0;ni<WN;ni++){
                acc[mi][ni] = __builtin_amdgcn_mfma_f32_16x16x32_bf16(
                    af[mi], bfr[ni], acc[mi][ni], 0, 0, 0);
            }
        }
        __builtin_amdgcn_s_setprio(0);
    }

    #pragma unroll
    for(int mi=0;mi<4;mi++){
        int gr0 = row0 + rowbase + mi*16 + kg*4;
        #pragma unroll
        for(int ni=0;ni<WN;ni++){
            int j = col0 + colbase + ni*16 + l15;
            #pragma unroll
            for(int rr=0;rr<4;rr++){
                int gr = gr0 + rr;
                if(gr < NN){
                    float a = acc[mi][ni][rr];
                    if(MODE == 0){
                        if(j < 256){
                            out0[(size_t)gr*256 + j] = 1.0f/(1.0f + expf(-(a + bias0[j])));
                        }else{
                            int jj = j - 256;
                            float rv = 1.0f/(1.0f + expf(-(a + bias1[jj])));
                            us v = f2bf(rv * h0[(size_t)gr*256 + jj]);
                            size_t base = (size_t)gr*512 + (size_t)(jj>>3)*16 + (jj&7);
                            out1[base] = v;
                            out1[base+8] = v;
                        }
                    }else{
                        float z = Zin[(size_t)gr*256 + j];
                        float ht = tanhf(a + bias0[j]);
                        float H = z*h0[(size_t)gr*256 + j] + (1.0f - z)*ht;
                        out0[(size_t)gr*256 + j] = fmaxf(H, 0.0f);
                    }
                }
            }
        }
    }
}

// ---------------- host ----------------

extern "C" void kernel_launch(void* const* d_in, const int* in_sizes, int n_in,
                              void* d_out, int out_size, void* d_ws, size_t ws_size,
                              hipStream_t stream){
    const float* x   = (const float*)d_in[0];
    const int*   ei  = (const int*)  d_in[1];
    const float* h0  = (const float*)d_in[2];
    const float* w1  = (const float*)d_in[3];
    const float* b1  = (const float*)d_in[4];
    const float* g1  = (const float*)d_in[5];
    const float* be1 = (const float*)d_in[6];
    const float* w2  = (const float*)d_in[7];
    const float* b2  = (const float*)d_in[8];
    const float* g2  = (const float*)d_in[9];
    const float* be2 = (const float*)d_in[10];
    const float* Wz  = (const float*)d_in[11];
    const float* bz  = (const float*)d_in[12];
    const float* Wr  = (const float*)d_in[13];
    const float* br  = (const float*)d_in[14];
    const float* Wh  = (const float*)d_in[15];
    const float* bh  = (const float*)d_in[16];
    float* out = (float*)d_out;
    float* wsf = (float*)d_ws;
    (void)in_sizes; (void)n_in; (void)out_size;

    // word (4B) offsets
    const size_t O_DEGO=0, O_DEGI=20000, O_CNT=40000, O_BN=60000;      // zero: 60256
    const size_t O_COLOFF=60288, O_EW=80384, O_INVDEG=720384;
    const size_t O_WTZR=740480, O_WTH=1395840;
    const size_t O_XPRE=1723520;
    const size_t O_XG=4283520;                 // 5 bufs x 5,120,000 words
    const size_t O_RG=29883520;                // 3 bufs x 5,120,000 words
    const size_t O_Z=45243520;                 // 20000x256 f32
    const size_t O_BF=50363520;                // conv2 folded weights, 2560 words
    const size_t WS_NEED_BYTES = (size_t)50366080 * 4;   // ~201.5 MB (236 MB proven)
    if(ws_size < WS_NEED_BYTES) return;

    const size_t SW = 5120000;

    int* degout = (int*)(wsf + O_DEGO);
    int* degin  = (int*)(wsf + O_DEGI);
    int* cnt    = (int*)(wsf + O_CNT);
    float* bn   = wsf + O_BN;          // [0:64)s1 [64:128)scsh1 [128:192)s2 [192:256)scsh2 [256:288)biasc
    int* coloff = (int*)(wsf + O_COLOFF);
    int2* ew    = (int2*)(wsf + O_EW);
    float* invdeg = wsf + O_INVDEG;
    us* Wtzr = (us*)(wsf + O_WTZR);
    us* Wth  = (us*)(wsf + O_WTH);
    us* Xpre = (us*)(wsf + O_XPRE);
    us* XG   = (us*)(wsf + O_XG);
    us* RG   = (us*)(wsf + O_RG);
    us* XHp  = XG;
    us* T1op = (us*)(wsf + O_XG + SW);
    us* T1ip = (us*)(wsf + O_XG + 2*SW);
    us* P2op = (us*)(wsf + O_XG + 3*SW);
    us* P2ip = (us*)(wsf + O_XG + 4*SW);
    us* RHp  = RG;
    us* Q1p  = (us*)(wsf + O_RG + SW);
    us* Q2p  = (us*)(wsf + O_RG + 2*SW);
    float* Z = wsf + O_Z;
    us* Bf   = (us*)(wsf + O_BF);
    us* y1T  = T1op;   // dead during CNN

    // graph CSR
    k_zero<<<236,256,0,stream>>>((uint32_t*)(wsf + O_DEGO), 60256);
    k_degree<<<1250,256,0,stream>>>(ei, degout, degin);
    k_scan<<<1,1024,0,stream>>>(degin, coloff, invdeg);
    k_csr<<<1250,256,0,stream>>>(ei, degout, coloff, cnt, ew);

    // CNN embedding
    k_conv1<<<2500,256,0,stream>>>(x, w1, b1, y1T);
    k_chanstats_T<<<256,256,0,stream>>>(y1T, bn+0);
    k_bnfin<<<1,32,0,stream>>>(bn+0, g1, be1, bn+64, 1.0f/620000.0f);
    k_wfold<<<40,256,0,stream>>>(w2, bn+64, Bf);
    k_wbias<<<1,256,0,stream>>>(w2, bn+64, b2, bn+256);
    k_conv2m<<<2500,256,0,stream>>>(y1T, Bf, bn+256, Xpre);
    k_chanstats_bf<256,8><<<64,256,0,stream>>>(Xpre, bn+128);
    k_bnfin<<<1,32,0,stream>>>(bn+128, g2, be2, bn+192, 1.0f/160000.0f);
    k_prep<<<5000,256,0,stream>>>(Xpre, bn+192, h0, XHp);

    // effective weights (transposed bf16, coalesced)
    k_wefft<512><<<320,256,0,stream>>>(Wz, Wr, Wtzr);
    k_wefft<256><<<160,256,0,stream>>>(Wh, Wh, Wth);

    // hop1 + hop2 props
    k_prop1<<<5000,256,0,stream>>>(XHp, coloff, ew, invdeg, T1op, T1ip);
    k_prop2<<<5000,256,0,stream>>>(T1op, T1ip, coloff, ew, invdeg, P2op, P2ip);

    // Z,R GEMM (fused sigmoid; RHp = bf16(sigmoid(r)*h0), duplicated halves)
    k_gemm<0,128><<<640,256,0,stream>>>(XG, RG, Wtzr, bz, br, h0, nullptr, Z, RHp);

    // props of RH
    k_propu<<<5000,256,0,stream>>>(RHp, coloff, ew, invdeg, Q1p);
    k_propu<<<5000,256,0,stream>>>(Q1p, coloff, ew, invdeg, Q2p);

    // H~ GEMM (fused tanh + gate + relu -> out)
    k_gemm<1,64><<<640,256,0,stream>>>(XG, RG, Wth, bh, nullptr, h0, Z, out, nullptr);
}

// Round 12
// 720.126 us; speedup vs baseline: 1.3877x; 1.0933x over previous
//
#include <hip/hip_runtime.h>
#include <cstdint>
#include <cstddef>

#define NN 20000
#define NE 320000
#define SBUF 10240000   // shorts per [node][512] buffer

typedef float f32x4 __attribute__((ext_vector_type(4)));
typedef short s16x8 __attribute__((ext_vector_type(8)));
typedef unsigned short us;

__device__ __forceinline__ us f2bf(float x){
    unsigned u = __float_as_uint(x);
    unsigned r = (u + 0x7fffu + ((u >> 16) & 1u)) >> 16;
    return (us)r;
}
__device__ __forceinline__ float bf2f(us s){
    return __uint_as_float(((unsigned)s) << 16);
}

__device__ __forceinline__ void gl16(const void* g, void* l){
    __builtin_amdgcn_global_load_lds((const __attribute__((address_space(1))) unsigned int*)g,
                                     (__attribute__((address_space(3))) unsigned int*)l, 16, 0, 0);
}

__device__ __forceinline__ void upd8(uint4 v, float w, float* ao, float* ai){
    float f0=__uint_as_float(v.x<<16), f1=__uint_as_float(v.x&0xffff0000u);
    float f2=__uint_as_float(v.y<<16), f3=__uint_as_float(v.y&0xffff0000u);
    float f4=__uint_as_float(v.z<<16), f5=__uint_as_float(v.z&0xffff0000u);
    float f6=__uint_as_float(v.w<<16), f7=__uint_as_float(v.w&0xffff0000u);
    ao[0]=fmaf(w,f0,ao[0]); ao[1]=fmaf(w,f1,ao[1]); ao[2]=fmaf(w,f2,ao[2]); ao[3]=fmaf(w,f3,ao[3]);
    ao[4]=fmaf(w,f4,ao[4]); ao[5]=fmaf(w,f5,ao[5]); ao[6]=fmaf(w,f6,ao[6]); ao[7]=fmaf(w,f7,ao[7]);
    ai[0]+=f0; ai[1]+=f1; ai[2]+=f2; ai[3]+=f3; ai[4]+=f4; ai[5]+=f5; ai[6]+=f6; ai[7]+=f7;
}
__device__ __forceinline__ void updw(uint4 v, float w, float* a){
    float f0=__uint_as_float(v.x<<16), f1=__uint_as_float(v.x&0xffff0000u);
    float f2=__uint_as_float(v.y<<16), f3=__uint_as_float(v.y&0xffff0000u);
    float f4=__uint_as_float(v.z<<16), f5=__uint_as_float(v.z&0xffff0000u);
    float f6=__uint_as_float(v.w<<16), f7=__uint_as_float(v.w&0xffff0000u);
    a[0]=fmaf(w,f0,a[0]); a[1]=fmaf(w,f1,a[1]); a[2]=fmaf(w,f2,a[2]); a[3]=fmaf(w,f3,a[3]);
    a[4]=fmaf(w,f4,a[4]); a[5]=fmaf(w,f5,a[5]); a[6]=fmaf(w,f6,a[6]); a[7]=fmaf(w,f7,a[7]);
}
__device__ __forceinline__ uint4 pack8(const float* a){
    uint4 r;
    r.x=((unsigned)f2bf(a[1])<<16)|f2bf(a[0]);
    r.y=((unsigned)f2bf(a[3])<<16)|f2bf(a[2]);
    r.z=((unsigned)f2bf(a[5])<<16)|f2bf(a[4]);
    r.w=((unsigned)f2bf(a[7])<<16)|f2bf(a[6]);
    return r;
}
__device__ __forceinline__ uint4 pack8s(const float* a, float s){
    uint4 r;
    r.x=((unsigned)f2bf(s*a[1])<<16)|f2bf(s*a[0]);
    r.y=((unsigned)f2bf(s*a[3])<<16)|f2bf(s*a[2]);
    r.z=((unsigned)f2bf(s*a[5])<<16)|f2bf(s*a[4]);
    r.w=((unsigned)f2bf(s*a[7])<<16)|f2bf(s*a[6]);
    return r;
}

// ---------------- init / graph ----------------

__global__ void k_zero(uint32_t* p, int n){
    int i = blockIdx.x*256 + threadIdx.x;
    if(i < n) p[i] = 0u;
}

__global__ void k_degree(const int* __restrict__ ei, int* degout, int* degin){
    int e = blockIdx.x*256 + threadIdx.x;
    if(e < NE){
        atomicAdd(&degout[ei[e]], 1);
        atomicAdd(&degin[ei[NE+e]], 1);
    }
}

__global__ void k_scan(const int* __restrict__ degin, int* __restrict__ coloff,
                       float* __restrict__ invdegin){
    __shared__ int part[1024];
    int t = threadIdx.x;
    int base = t*20;
    int s = 0;
    for(int k=0;k<20;k++){ int i = base+k; if(i < NN) s += degin[i]; }
    part[t] = s;
    __syncthreads();
    for(int off=1; off<1024; off<<=1){
        int v = (t>=off) ? part[t-off] : 0;
        __syncthreads();
        part[t] += v;
        __syncthreads();
    }
    int run = (t>0) ? part[t-1] : 0;
    for(int k=0;k<20;k++){
        int i = base+k;
        if(i < NN){
            int d = degin[i];
            coloff[i] = run;
            run += d;
            invdegin[i] = (d>0) ? (1.0f/(float)d) : 0.0f;
        }
    }
    if(t==1023) coloff[NN] = part[1023];
}

__global__ void k_csr(const int* __restrict__ ei, const int* __restrict__ degout,
                      const int* __restrict__ coloff, int* cnt, int2* __restrict__ ew){
    int e = blockIdx.x*256 + threadIdx.x;
    if(e < NE){
        int r = ei[e], c = ei[NE+e];
        int pos = coloff[c] + atomicAdd(&cnt[c], 1);
        int2 v; v.x = r; v.y = __float_as_int(1.0f/(float)degout[r]);
        ew[pos] = v;
    }
}

// ---------------- CNN embedding ----------------
// y1T layout: [node][pos 0..31][c 0..31] bf16, pos 31 zeroed

__global__ void k_conv1(const float* __restrict__ x, const float* __restrict__ w1,
                        const float* __restrict__ b1, us* __restrict__ y1T){
    __shared__ float w[320];
    __shared__ float bb[32];
    int t = threadIdx.x;
    for(int i=t;i<320;i+=256) w[i] = w1[i];
    if(t < 32) bb[t] = b1[t];
    __syncthreads();
    int gid = blockIdx.x*256 + t;
    int node = gid>>5, p = gid&31;
    us* yo = y1T + (size_t)node*1024 + p*32;
    if(p >= 31){
        uint4 z = {0,0,0,0};
        *(uint4*)yo = z; *(uint4*)(yo+8) = z;
        *(uint4*)(yo+16) = z; *(uint4*)(yo+24) = z;
        return;
    }
    const float* xr = x + node*100 + 3*p;
    float xv[10];
    #pragma unroll
    for(int k=0;k<10;k++) xv[k] = xr[k];
    float o[32];
    #pragma unroll
    for(int c=0;c<32;c++){
        float a = bb[c];
        #pragma unroll
        for(int k=0;k<10;k++) a = fmaf(w[c*10+k], xv[k], a);
        o[c] = fmaxf(a, 0.0f);
    }
    *(uint4*)yo      = pack8(o);
    *(uint4*)(yo+8)  = pack8(o+8);
    *(uint4*)(yo+16) = pack8(o+16);
    *(uint4*)(yo+24) = pack8(o+24);
}

__global__ void k_chanstats_T(const us* __restrict__ y, float* __restrict__ sq){
    int tid = blockIdx.x*256 + threadIdx.x;
    int slot = tid & 1023;
    int c = slot & 31;
    int node0 = tid >> 10;
    float s = 0.f, q = 0.f;
    for(int n=node0; n<NN; n+=64){
        float v = bf2f(y[(size_t)n*1024 + slot]);
        s += v; q = fmaf(v, v, q);
    }
    s += __shfl_xor(s, 32);
    q += __shfl_xor(q, 32);
    if((threadIdx.x & 63) < 32){
        atomicAdd(&sq[c], s);
        atomicAdd(&sq[32+c], q);
    }
}

template<int SLOTS, int PPC>
__global__ void k_chanstats_bf(const us* __restrict__ y, float* __restrict__ sq){
    int tid = blockIdx.x*blockDim.x + threadIdx.x;
    int slot = tid & (SLOTS-1);
    int node0 = tid / SLOTS;
    int nstride = (gridDim.x*blockDim.x) / SLOTS;
    int c = slot / PPC;
    float s = 0.f, q = 0.f;
    for(int n=node0; n<NN; n+=nstride){
        float v = bf2f(y[(size_t)n*SLOTS + slot]);
        s += v; q = fmaf(v, v, q);
    }
    #pragma unroll
    for(int m=PPC>>1; m>0; m>>=1){
        s += __shfl_xor(s, m);
        q += __shfl_xor(q, m);
    }
    if((threadIdx.x & (PPC-1)) == 0){
        atomicAdd(&sq[c], s);
        atomicAdd(&sq[32+c], q);
    }
}

__global__ void k_bnfin(const float* __restrict__ sq, const float* __restrict__ gamma,
                        const float* __restrict__ beta, float* __restrict__ scsh,
                        float inv_count){
    int c = threadIdx.x;
    if(c < 32){
        float m = sq[c]*inv_count;
        float v = sq[32+c]*inv_count - m*m;
        float sc = gamma[c]*rsqrtf(v + 1e-5f);
        scsh[c] = sc;
        scsh[32+c] = beta[c] - m*sc;
    }
}

__global__ void k_wfold(const float* __restrict__ w2, const float* __restrict__ scsh1,
                        us* __restrict__ Bf){
    int idx = blockIdx.x*256 + threadIdx.x;
    if(idx >= 10240) return;
    int kk = idx >> 10, c2 = (idx >> 5) & 31, c = idx & 31;
    Bf[idx] = f2bf(scsh1[c] * w2[c2*320 + c*10 + kk]);
}

__global__ void k_wbias(const float* __restrict__ w2, const float* __restrict__ scsh1,
                        const float* __restrict__ b2, float* __restrict__ biasc){
    int t = threadIdx.x;
    int c2 = t >> 3, part = t & 7;
    float s = 0.f;
    for(int i=part; i<320; i+=8)
        s += scsh1[32 + i/10] * w2[c2*320 + i];
    s += __shfl_xor(s,1); s += __shfl_xor(s,2); s += __shfl_xor(s,4);
    if(part == 0) biasc[c2] = b2[c2] + s;
}

// conv2 via 10 shifted MFMAs
__global__ void __launch_bounds__(256) k_conv2m(const us* __restrict__ y1T,
        const us* __restrict__ Bf, const float* __restrict__ biasc,
        us* __restrict__ Xpre){
    int t = threadIdx.x;
    int wv = t>>6, l = t&63;
    int l15 = l&15, g = l>>4;
    int r0 = blockIdx.x*64 + wv*16;
    int arow = r0 + l15;
    int an = arow>>3, ap = arow&7;
    const us* abase = y1T + (size_t)an*1024 + (3*ap)*32 + g*8;
    const us* bbase = Bf + (size_t)l15*32 + g*8;
    f32x4 acc0 = {}, acc1 = {};
    #pragma unroll
    for(int kk=0;kk<10;kk++){
        s16x8 af = *(const s16x8*)(abase + kk*32);
        s16x8 b0 = *(const s16x8*)(bbase + kk*1024);
        s16x8 b1 = *(const s16x8*)(bbase + kk*1024 + 512);
        acc0 = __builtin_amdgcn_mfma_f32_16x16x32_bf16(af, b0, acc0, 0, 0, 0);
        acc1 = __builtin_amdgcn_mfma_f32_16x16x32_bf16(af, b1, acc1, 0, 0, 0);
    }
    int base = r0 + g*4;
    int n = base>>3, p0 = base&7;
    #pragma unroll
    for(int nf=0;nf<2;nf++){
        int c2 = nf*16 + l15;
        float bb = biasc[c2];
        f32x4 a = nf ? acc1 : acc0;
        float v0 = fmaxf(a[0]+bb,0.f), v1 = fmaxf(a[1]+bb,0.f);
        float v2 = fmaxf(a[2]+bb,0.f), v3 = fmaxf(a[3]+bb,0.f);
        uint2 pk;
        pk.x = ((unsigned)f2bf(v1)<<16)|f2bf(v0);
        pk.y = ((unsigned)f2bf(v3)<<16)|f2bf(v2);
        *(uint2*)&Xpre[(size_t)n*256 + c2*8 + p0] = pk;
    }
}

// build XHp [node][512]: chunk g: half0 = BN2(X)[g*8..], half1 = h0[g*8..]
__global__ void __launch_bounds__(256) k_prep(const us* __restrict__ Xpre,
        const float* __restrict__ scsh, const float* __restrict__ h0,
        us* __restrict__ XHp){
    int node = blockIdx.x*4 + (threadIdx.x>>6);
    if(node >= NN) return;
    int lane = threadIdx.x & 63;
    int half = lane>>5, g = lane&31;
    uint4 o;
    if(half == 0){
        uint4 v = *(const uint4*)(Xpre + (size_t)node*256 + g*8);
        float sc = scsh[g], sh = scsh[32+g];
        float y[8];
        y[0]=fmaf(sc,__uint_as_float(v.x<<16),sh); y[1]=fmaf(sc,__uint_as_float(v.x&0xffff0000u),sh);
        y[2]=fmaf(sc,__uint_as_float(v.y<<16),sh); y[3]=fmaf(sc,__uint_as_float(v.y&0xffff0000u),sh);
        y[4]=fmaf(sc,__uint_as_float(v.z<<16),sh); y[5]=fmaf(sc,__uint_as_float(v.z&0xffff0000u),sh);
        y[6]=fmaf(sc,__uint_as_float(v.w<<16),sh); y[7]=fmaf(sc,__uint_as_float(v.w&0xffff0000u),sh);
        o = pack8(y);
    }else{
        float4 a = *(const float4*)(h0 + (size_t)node*256 + g*8);
        float4 b = *(const float4*)(h0 + (size_t)node*256 + g*8 + 4);
        float y[8] = {a.x,a.y,a.z,a.w,b.x,b.y,b.z,b.w};
        o = pack8(y);
    }
    *(uint4*)(XHp + (size_t)node*512 + (size_t)g*16 + half*8) = o;
}

// ---------------- effective weights (transposed bf16, coalesced via LDS) ----------------

__device__ __forceinline__ float weff_val(const float* W, int term, size_t base){
    const size_t S = 512*256;
    if(term==0)      return W[0*S+base] + W[3*S+base] - W[2*S+base] - W[5*S+base];
    else if(term==1) return W[1*S+base];
    else if(term==2) return W[4*S+base];
    else if(term==3) return 2.0f*W[2*S+base];
    else             return 2.0f*W[5*S+base];
}

template<int NCOL>
__global__ void __launch_bounds__(256) k_wefft(const float* __restrict__ Wa,
        const float* __restrict__ Wb, us* __restrict__ Wt){
    __shared__ float tile[64*65];
    int bx = blockIdx.x;
    constexpr int CT = NCOL/64;
    int kb = bx / (CT*4);
    int rem = bx % (CT*4);
    int ct = rem >> 2, rt = rem & 3;
    int col0 = ct*64, rr0 = rt*64;
    const float* W = (col0 < 256) ? Wa : Wb;
    int jb = col0 & 255;
    int term = kb >> 1, half = kb & 1;
    int t = threadIdx.x;
    int j_l = t & 63, r4 = t >> 6;
    #pragma unroll
    for(int it=0; it<16; it++){
        int rr_l = it*4 + r4;
        int row = half*256 + rr0 + rr_l;
        size_t base = (size_t)row*256 + jb + j_l;
        tile[j_l*65 + rr_l] = weff_val(W, term, base);
    }
    __syncthreads();
    int rr_w = t & 63;
    #pragma unroll
    for(int it=0; it<16; it++){
        int col_l = it*4 + r4;
        Wt[(size_t)(col0+col_l)*2560 + kb*256 + rr0 + rr_w] = f2bf(tile[col_l*65 + rr_w]);
    }
}

// ---------------- propagation ----------------

__global__ void __launch_bounds__(256) k_prop1(const us* __restrict__ XHp,
        const int* __restrict__ coloff, const int2* __restrict__ ew,
        const float* __restrict__ invdeg, us* __restrict__ T1op, us* __restrict__ T1ip){
    int node = blockIdx.x*4 + (threadIdx.x>>6);
    if(node >= NN) return;
    int lane = threadIdx.x & 63;
    size_t lo = (size_t)(lane&31)*16 + (lane>>5)*8;
    int s = __builtin_amdgcn_readfirstlane(coloff[node]);
    int e = __builtin_amdgcn_readfirstlane(coloff[node+1]);
    float ao[8]={0,0,0,0,0,0,0,0}, ai[8]={0,0,0,0,0,0,0,0};
    int j = s;
    for(; j+7 < e; j += 8){
        int2 ed[8]; uint4 v[8];
        #pragma unroll
        for(int i=0;i<8;i++) ed[i] = ew[j+i];
        #pragma unroll
        for(int i=0;i<8;i++) v[i] = *(const uint4*)(XHp+(size_t)ed[i].x*512+lo);
        #pragma unroll
        for(int i=0;i<8;i++) upd8(v[i], __int_as_float(ed[i].y), ao, ai);
    }
    for(; j < e; j++){
        int2 ed = ew[j];
        uint4 v = *(const uint4*)(XHp+(size_t)ed.x*512+lo);
        upd8(v, __int_as_float(ed.y), ao, ai);
    }
    float wi = invdeg[node];
    *(uint4*)(T1op+(size_t)node*512+lo) = pack8(ao);
    *(uint4*)(T1ip+(size_t)node*512+lo) = pack8s(ai,wi);
}

__global__ void __launch_bounds__(256) k_prop2(const us* __restrict__ T1op,
        const us* __restrict__ T1ip,
        const int* __restrict__ coloff, const int2* __restrict__ ew,
        const float* __restrict__ invdeg, us* __restrict__ P2op, us* __restrict__ P2ip){
    int node = blockIdx.x*4 + (threadIdx.x>>6);
    if(node >= NN) return;
    int lane = threadIdx.x & 63;
    size_t lo = (size_t)(lane&31)*16 + (lane>>5)*8;
    int s = __builtin_amdgcn_readfirstlane(coloff[node]);
    int e = __builtin_amdgcn_readfirstlane(coloff[node+1]);
    float ao[8]={0,0,0,0,0,0,0,0}, ai[8]={0,0,0,0,0,0,0,0};
    int j = s;
    for(; j+3 < e; j += 4){
        int2 ed[4]; uint4 va[4], vb[4];
        #pragma unroll
        for(int i=0;i<4;i++) ed[i] = ew[j+i];
        #pragma unroll
        for(int i=0;i<4;i++){
            size_t o = (size_t)ed[i].x*512+lo;
            va[i] = *(const uint4*)(T1op+o);
            vb[i] = *(const uint4*)(T1ip+o);
        }
        #pragma unroll
        for(int i=0;i<4;i++){
            updw(va[i], __int_as_float(ed[i].y), ao);
            updw(vb[i], 1.0f, ai);
        }
    }
    for(; j < e; j++){
        int2 ed = ew[j];
        size_t o = (size_t)ed.x*512+lo;
        updw(*(const uint4*)(T1op+o), __int_as_float(ed.y), ao);
        updw(*(const uint4*)(T1ip+o), 1.0f, ai);
    }
    float wi = invdeg[node];
    *(uint4*)(P2op+(size_t)node*512+lo) = pack8(ao);
    *(uint4*)(P2ip+(size_t)node*512+lo) = pack8s(ai,wi);
}

// q1: prop of dense RHb [node][256]; lane-halves take alternate edges, shfl combine.
__global__ void __launch_bounds__(256) k_propq1(const us* __restrict__ RHb,
        const int* __restrict__ coloff, const int2* __restrict__ ew,
        const float* __restrict__ invdeg, us* __restrict__ Q1p){
    int node = blockIdx.x*4 + (threadIdx.x>>6);
    if(node >= NN) return;
    int lane = threadIdx.x & 63;
    int half = lane>>5, g = lane&31;
    int s = __builtin_amdgcn_readfirstlane(coloff[node]);
    int e = __builtin_amdgcn_readfirstlane(coloff[node+1]);
    float ao[8]={0,0,0,0,0,0,0,0}, ai[8]={0,0,0,0,0,0,0,0};
    int j = s;
    for(; j+3 < e; j += 4){
        int2 e0 = ew[j+half], e1 = ew[j+2+half];
        uint4 v0 = *(const uint4*)(RHb+(size_t)e0.x*256+g*8);
        uint4 v1 = *(const uint4*)(RHb+(size_t)e1.x*256+g*8);
        upd8(v0, __int_as_float(e0.y), ao, ai);
        upd8(v1, __int_as_float(e1.y), ao, ai);
    }
    for(; j+1 < e; j += 2){
        int2 ed = ew[j+half];
        uint4 v = *(const uint4*)(RHb+(size_t)ed.x*256+g*8);
        upd8(v, __int_as_float(ed.y), ao, ai);
    }
    if(j < e && half == 0){
        int2 ed = ew[j];
        uint4 v = *(const uint4*)(RHb+(size_t)ed.x*256+g*8);
        upd8(v, __int_as_float(ed.y), ao, ai);
    }
    #pragma unroll
    for(int k=0;k<8;k++){
        ao[k] += __shfl_xor(ao[k],32);
        ai[k] += __shfl_xor(ai[k],32);
    }
    if(half == 0){
        float wi = invdeg[node];
        *(uint4*)(Q1p+(size_t)node*512+(size_t)g*16)   = pack8(ao);
        *(uint4*)(Q1p+(size_t)node*512+(size_t)g*16+8) = pack8s(ai,wi);
    }
}

// q2: prop of Q1p pair (o-half weighted, i-half plain + invdeg)
__global__ void __launch_bounds__(256) k_propu(const us* __restrict__ Yin,
        const int* __restrict__ coloff, const int2* __restrict__ ew,
        const float* __restrict__ invdeg, us* __restrict__ Pout){
    int node = blockIdx.x*4 + (threadIdx.x>>6);
    if(node >= NN) return;
    int lane = threadIdx.x & 63;
    int half = lane>>5;
    size_t lo = (size_t)(lane&31)*16 + half*8;
    int s = __builtin_amdgcn_readfirstlane(coloff[node]);
    int e = __builtin_amdgcn_readfirstlane(coloff[node+1]);
    float a[8]={0,0,0,0,0,0,0,0};
    int j = s;
    for(; j+7 < e; j += 8){
        int2 ed[8]; uint4 v[8];
        #pragma unroll
        for(int i=0;i<8;i++) ed[i] = ew[j+i];
        #pragma unroll
        for(int i=0;i<8;i++) v[i] = *(const uint4*)(Yin+(size_t)ed[i].x*512+lo);
        #pragma unroll
        for(int i=0;i<8;i++) updw(v[i], half ? 1.0f : __int_as_float(ed[i].y), a);
    }
    for(; j < e; j++){
        int2 ed = ew[j];
        uint4 v = *(const uint4*)(Yin+(size_t)ed.x*512+lo);
        updw(v, half ? 1.0f : __int_as_float(ed.y), a);
    }
    float sc = half ? invdeg[node] : 1.0f;
    *(uint4*)(Pout+(size_t)node*512+lo) = pack8s(a,sc);
}

// ---------------- bf16 MFMA GEMM: 64-row tiles, 2-buffer counted-vmcnt (round-8 body) ----------------
// Grid 1280: xcd=bid&7, s=bid>>3, cidx=s&3, r=(s>>2)*8+xcd (<313). Tile 64 x BNT.

template<int MODE, int BNT>
__global__ void __launch_bounds__(256) k_gemm(const us* __restrict__ XG,
        const us* __restrict__ RG, const us* __restrict__ Wt,
        const float* __restrict__ bias0, const float* __restrict__ bias1,
        const float* __restrict__ h0, const float* __restrict__ Zin,
        float* __restrict__ out0, us* __restrict__ out1){
    constexpr int WN = BNT/32;          // B frags per wave
    constexpr int NB = BNT/64;          // B gl16 per thread per step
    constexpr int NVM = 1 + NB;         // loads per stage
    __shared__ us As[2][2048];
    __shared__ us Bs[2][BNT*32];
    int t = threadIdx.x;
    int wid = t >> 6, lane = t & 63;
    int l15 = lane & 15, kg = lane >> 4;

    int bid = blockIdx.x;
    int xcd = bid & 7, sblk = bid >> 3;
    int cidx = sblk & 3, r = (sblk >> 2)*8 + xcd;
    if(r >= 313) return;
    int row0 = r*64, col0 = cidx*BNT;
    int rowbase = (wid >> 1)*32, colbase = (wid & 1)*(BNT/2);
    int swz = (l15 >> 1) & 3;

    // A staging: 1 chunk/thread
    int srA = t >> 2;
    int sgA = (t & 3) ^ ((srA >> 1) & 3);
    int grA = row0 + srA; grA = (grA < NN) ? grA : NN-1;
    size_t rowoffA = (size_t)grA*512 + (size_t)sgA*16;
    // B staging
    int srB[NB], sgB[NB];
    size_t coloffB[NB];
    #pragma unroll
    for(int i=0;i<NB;i++){
        int c = t + i*256;
        srB[i] = c >> 2;
        sgB[i] = (c & 3) ^ ((srB[i] >> 1) & 3);
        coloffB[i] = (size_t)(col0+srB[i])*2560 + (size_t)sgB[i]*8;
    }

    f32x4 acc[2][WN] = {};

    auto stage = [&](int buf, int s){
        int kb = s >> 3;
        int ktc = (s & 7) * 4;
        if(MODE == 1 && kb == 1){
            gl16(RG + (rowoffA >> 1) + (size_t)ktc*8, &As[buf][t*8]);
        }else{
            const us* Ap;
            if(MODE == 0){
                Ap = XG + (size_t)(kb >> 1) * SBUF + (size_t)(kb & 1) * 8;
            }else{
                if((kb & 1) == 0) Ap = XG + (size_t)(kb >> 1) * SBUF;
                else Ap = RG + (size_t)((kb + 1) >> 2) * SBUF + (size_t)(((kb + 1) >> 1) & 1) * 8;
            }
            gl16(Ap + rowoffA + (size_t)ktc*16, &As[buf][t*8]);
        }
        const us* Wp = Wt + (size_t)kb*256 + (s & 7)*32;
        #pragma unroll
        for(int i=0;i<NB;i++)
            gl16(Wp + coloffB[i], &Bs[buf][(t+i*256)*8]);
    };

    stage(0, 0);
    stage(1, 1);
    for(int step=0; step<80; ++step){
        int cur = step & 1;
        if(step < 79){
            if(NVM == 3) asm volatile("s_waitcnt vmcnt(3)" ::: "memory");
            else         asm volatile("s_waitcnt vmcnt(2)" ::: "memory");
        }else{
            asm volatile("s_waitcnt vmcnt(0)" ::: "memory");
        }
        __builtin_amdgcn_s_barrier();
        s16x8 af[2], bfr[WN];
        #pragma unroll
        for(int i=0;i<2;i++){
            int row = rowbase + i*16 + l15;
            af[i] = *(const s16x8*)&As[cur][(row*4 + (kg ^ swz))*8];
        }
        #pragma unroll
        for(int n=0;n<WN;n++){
            int colr = colbase + n*16 + l15;
            bfr[n] = *(const s16x8*)&Bs[cur][(colr*4 + (kg ^ swz))*8];
        }
        asm volatile("s_waitcnt lgkmcnt(0)" ::: "memory");
        __builtin_amdgcn_sched_barrier(0);
        __builtin_amdgcn_s_barrier();
        if(step < 78) stage(cur, step+2);
        __builtin_amdgcn_s_setprio(1);
        #pragma unroll
        for(int mi=0;mi<2;mi++){
            #pragma unroll
            for(int ni=0;ni<WN;ni++){
                acc[mi][ni] = __builtin_amdgcn_mfma_f32_16x16x32_bf16(
                    af[mi], bfr[ni], acc[mi][ni], 0, 0, 0);
            }
        }
        __builtin_amdgcn_s_setprio(0);
    }

    #pragma unroll
    for(int mi=0;mi<2;mi++){
        int gr0 = row0 + rowbase + mi*16 + kg*4;
        #pragma unroll
        for(int ni=0;ni<WN;ni++){
            int j = col0 + colbase + ni*16 + l15;
            #pragma unroll
            for(int rr=0;rr<4;rr++){
                int gr = gr0 + rr;
                if(gr < NN){
                    float a = acc[mi][ni][rr];
                    if(MODE == 0){
                        if(j < 256){
                            out0[(size_t)gr*256 + j] = 1.0f/(1.0f + expf(-(a + bias0[j])));
                        }else{
                            int jj = j - 256;
                            float rv = 1.0f/(1.0f + expf(-(a + bias1[jj])));
                            out1[(size_t)gr*256 + jj] = f2bf(rv * h0[(size_t)gr*256 + jj]);
                        }
                    }else{
                        float z = Zin[(size_t)gr*256 + j];
                        float ht = tanhf(a + bias0[j]);
                        float H = z*h0[(size_t)gr*256 + j] + (1.0f - z)*ht;
                        out0[(size_t)gr*256 + j] = fmaxf(H, 0.0f);
                    }
                }
            }
        }
    }
}

// ---------------- host ----------------

extern "C" void kernel_launch(void* const* d_in, const int* in_sizes, int n_in,
                              void* d_out, int out_size, void* d_ws, size_t ws_size,
                              hipStream_t stream){
    const float* x   = (const float*)d_in[0];
    const int*   ei  = (const int*)  d_in[1];
    const float* h0  = (const float*)d_in[2];
    const float* w1  = (const float*)d_in[3];
    const float* b1  = (const float*)d_in[4];
    const float* g1  = (const float*)d_in[5];
    const float* be1 = (const float*)d_in[6];
    const float* w2  = (const float*)d_in[7];
    const float* b2  = (const float*)d_in[8];
    const float* g2  = (const float*)d_in[9];
    const float* be2 = (const float*)d_in[10];
    const float* Wz  = (const float*)d_in[11];
    const float* bz  = (const float*)d_in[12];
    const float* Wr  = (const float*)d_in[13];
    const float* br  = (const float*)d_in[14];
    const float* Wh  = (const float*)d_in[15];
    const float* bh  = (const float*)d_in[16];
    float* out = (float*)d_out;
    float* wsf = (float*)d_ws;
    (void)in_sizes; (void)n_in; (void)out_size;

    // word (4B) offsets
    const size_t O_DEGO=0, O_DEGI=20000, O_CNT=40000, O_BN=60000;      // zero: 60256
    const size_t O_COLOFF=60288, O_EW=80384, O_INVDEG=720384;
    const size_t O_WTZR=740480, O_WTH=1395840;
    const size_t O_XPRE=1723520;
    const size_t O_XG=4283520;                 // 5 bufs x 5,120,000 words
    const size_t O_RG=29883520;                // RHb dense (2.56M) + Q1p + Q2p
    const size_t O_Z=45243520;                 // 20000x256 f32
    const size_t O_BF=50363520;                // conv2 folded weights
    const size_t WS_NEED_BYTES = (size_t)50366080 * 4;
    if(ws_size < WS_NEED_BYTES) return;

    const size_t SW = 5120000;

    int* degout = (int*)(wsf + O_DEGO);
    int* degin  = (int*)(wsf + O_DEGI);
    int* cnt    = (int*)(wsf + O_CNT);
    float* bn   = wsf + O_BN;
    int* coloff = (int*)(wsf + O_COLOFF);
    int2* ew    = (int2*)(wsf + O_EW);
    float* invdeg = wsf + O_INVDEG;
    us* Wtzr = (us*)(wsf + O_WTZR);
    us* Wth  = (us*)(wsf + O_WTH);
    us* Xpre = (us*)(wsf + O_XPRE);
    us* XG   = (us*)(wsf + O_XG);
    us* RG   = (us*)(wsf + O_RG);      // RHb dense [node][256]
    us* XHp  = XG;
    us* T1op = (us*)(wsf + O_XG + SW);
    us* T1ip = (us*)(wsf + O_XG + 2*SW);
    us* P2op = (us*)(wsf + O_XG + 3*SW);
    us* P2ip = (us*)(wsf + O_XG + 4*SW);
    us* RHb  = RG;
    us* Q1p  = (us*)(wsf + O_RG + SW);     // pair [node][512]
    us* Q2p  = (us*)(wsf + O_RG + 2*SW);   // pair [node][512]
    float* Z = wsf + O_Z;
    us* Bf   = (us*)(wsf + O_BF);
    us* y1T  = T1op;   // dead during CNN

    // graph CSR
    k_zero<<<236,256,0,stream>>>((uint32_t*)(wsf + O_DEGO), 60256);
    k_degree<<<1250,256,0,stream>>>(ei, degout, degin);
    k_scan<<<1,1024,0,stream>>>(degin, coloff, invdeg);
    k_csr<<<1250,256,0,stream>>>(ei, degout, coloff, cnt, ew);

    // CNN embedding
    k_conv1<<<2500,256,0,stream>>>(x, w1, b1, y1T);
    k_chanstats_T<<<256,256,0,stream>>>(y1T, bn+0);
    k_bnfin<<<1,32,0,stream>>>(bn+0, g1, be1, bn+64, 1.0f/620000.0f);
    k_wfold<<<40,256,0,stream>>>(w2, bn+64, Bf);
    k_wbias<<<1,256,0,stream>>>(w2, bn+64, b2, bn+256);
    k_conv2m<<<2500,256,0,stream>>>(y1T, Bf, bn+256, Xpre);
    k_chanstats_bf<256,8><<<64,256,0,stream>>>(Xpre, bn+128);
    k_bnfin<<<1,32,0,stream>>>(bn+128, g2, be2, bn+192, 1.0f/160000.0f);
    k_prep<<<5000,256,0,stream>>>(Xpre, bn+192, h0, XHp);

    // effective weights (transposed bf16, coalesced)
    k_wefft<512><<<320,256,0,stream>>>(Wz, Wr, Wtzr);
    k_wefft<256><<<160,256,0,stream>>>(Wh, Wh, Wth);

    // hop1 + hop2 props
    k_prop1<<<5000,256,0,stream>>>(XHp, coloff, ew, invdeg, T1op, T1ip);
    k_prop2<<<5000,256,0,stream>>>(T1op, T1ip, coloff, ew, invdeg, P2op, P2ip);

    // Z,R GEMM (fused sigmoid; RHb = bf16(sigmoid(r)*h0), dense 256)
    k_gemm<0,128><<<1280,256,0,stream>>>(XG, RG, Wtzr, bz, br, h0, nullptr, Z, RHb);

    // props of RH
    k_propq1<<<5000,256,0,stream>>>(RHb, coloff, ew, invdeg, Q1p);
    k_propu<<<5000,256,0,stream>>>(Q1p, coloff, ew, invdeg, Q2p);

    // H~ GEMM (fused tanh + gate + relu -> out)
    k_gemm<1,64><<<1280,256,0,stream>>>(XG, RG, Wth, bh, nullptr, h0, Z, out, nullptr);
}

// Round 13
// 706.722 us; speedup vs baseline: 1.4140x; 1.0190x over previous
//
#include <hip/hip_runtime.h>
#include <cstdint>
#include <cstddef>

#define NN 20000
#define NE 320000
#define SBUF 10240000   // shorts per [node][512] buffer

typedef float f32x4 __attribute__((ext_vector_type(4)));
typedef short s16x8 __attribute__((ext_vector_type(8)));
typedef unsigned short us;

__device__ __forceinline__ us f2bf(float x){
    unsigned u = __float_as_uint(x);
    unsigned r = (u + 0x7fffu + ((u >> 16) & 1u)) >> 16;
    return (us)r;
}
__device__ __forceinline__ float bf2f(us s){
    return __uint_as_float(((unsigned)s) << 16);
}

__device__ __forceinline__ void gl16(const void* g, void* l){
    __builtin_amdgcn_global_load_lds((const __attribute__((address_space(1))) unsigned int*)g,
                                     (__attribute__((address_space(3))) unsigned int*)l, 16, 0, 0);
}

__device__ __forceinline__ void upd8(uint4 v, float w, float* ao, float* ai){
    float f0=__uint_as_float(v.x<<16), f1=__uint_as_float(v.x&0xffff0000u);
    float f2=__uint_as_float(v.y<<16), f3=__uint_as_float(v.y&0xffff0000u);
    float f4=__uint_as_float(v.z<<16), f5=__uint_as_float(v.z&0xffff0000u);
    float f6=__uint_as_float(v.w<<16), f7=__uint_as_float(v.w&0xffff0000u);
    ao[0]=fmaf(w,f0,ao[0]); ao[1]=fmaf(w,f1,ao[1]); ao[2]=fmaf(w,f2,ao[2]); ao[3]=fmaf(w,f3,ao[3]);
    ao[4]=fmaf(w,f4,ao[4]); ao[5]=fmaf(w,f5,ao[5]); ao[6]=fmaf(w,f6,ao[6]); ao[7]=fmaf(w,f7,ao[7]);
    ai[0]+=f0; ai[1]+=f1; ai[2]+=f2; ai[3]+=f3; ai[4]+=f4; ai[5]+=f5; ai[6]+=f6; ai[7]+=f7;
}
__device__ __forceinline__ void updw(uint4 v, float w, float* a){
    float f0=__uint_as_float(v.x<<16), f1=__uint_as_float(v.x&0xffff0000u);
    float f2=__uint_as_float(v.y<<16), f3=__uint_as_float(v.y&0xffff0000u);
    float f4=__uint_as_float(v.z<<16), f5=__uint_as_float(v.z&0xffff0000u);
    float f6=__uint_as_float(v.w<<16), f7=__uint_as_float(v.w&0xffff0000u);
    a[0]=fmaf(w,f0,a[0]); a[1]=fmaf(w,f1,a[1]); a[2]=fmaf(w,f2,a[2]); a[3]=fmaf(w,f3,a[3]);
    a[4]=fmaf(w,f4,a[4]); a[5]=fmaf(w,f5,a[5]); a[6]=fmaf(w,f6,a[6]); a[7]=fmaf(w,f7,a[7]);
}
__device__ __forceinline__ uint4 pack8(const float* a){
    uint4 r;
    r.x=((unsigned)f2bf(a[1])<<16)|f2bf(a[0]);
    r.y=((unsigned)f2bf(a[3])<<16)|f2bf(a[2]);
    r.z=((unsigned)f2bf(a[5])<<16)|f2bf(a[4]);
    r.w=((unsigned)f2bf(a[7])<<16)|f2bf(a[6]);
    return r;
}
__device__ __forceinline__ uint4 pack8s(const float* a, float s){
    uint4 r;
    r.x=((unsigned)f2bf(s*a[1])<<16)|f2bf(s*a[0]);
    r.y=((unsigned)f2bf(s*a[3])<<16)|f2bf(s*a[2]);
    r.z=((unsigned)f2bf(s*a[5])<<16)|f2bf(s*a[4]);
    r.w=((unsigned)f2bf(s*a[7])<<16)|f2bf(s*a[6]);
    return r;
}

// ---------------- init / graph ----------------

__global__ void k_zero(uint32_t* p, int n){
    int i = blockIdx.x*256 + threadIdx.x;
    if(i < n) p[i] = 0u;
}

__global__ void k_degree(const int* __restrict__ ei, int* degout, int* degin){
    int e = blockIdx.x*256 + threadIdx.x;
    if(e < NE){
        atomicAdd(&degout[ei[e]], 1);
        atomicAdd(&degin[ei[NE+e]], 1);
    }
}

__global__ void k_scan(const int* __restrict__ degin, int* __restrict__ coloff,
                       float* __restrict__ invdegin){
    __shared__ int part[1024];
    int t = threadIdx.x;
    int base = t*20;
    int s = 0;
    for(int k=0;k<20;k++){ int i = base+k; if(i < NN) s += degin[i]; }
    part[t] = s;
    __syncthreads();
    for(int off=1; off<1024; off<<=1){
        int v = (t>=off) ? part[t-off] : 0;
        __syncthreads();
        part[t] += v;
        __syncthreads();
    }
    int run = (t>0) ? part[t-1] : 0;
    for(int k=0;k<20;k++){
        int i = base+k;
        if(i < NN){
            int d = degin[i];
            coloff[i] = run;
            run += d;
            invdegin[i] = (d>0) ? (1.0f/(float)d) : 0.0f;
        }
    }
    if(t==1023) coloff[NN] = part[1023];
}

__global__ void k_csr(const int* __restrict__ ei, const int* __restrict__ degout,
                      const int* __restrict__ coloff, int* cnt, int2* __restrict__ ew){
    int e = blockIdx.x*256 + threadIdx.x;
    if(e < NE){
        int r = ei[e], c = ei[NE+e];
        int pos = coloff[c] + atomicAdd(&cnt[c], 1);
        int2 v; v.x = r; v.y = __float_as_int(1.0f/(float)degout[r]);
        ew[pos] = v;
    }
}

// ---------------- CNN embedding ----------------
// y1T layout: [node][pos 0..31][c 0..31] bf16, pos 31 zeroed

__global__ void k_conv1(const float* __restrict__ x, const float* __restrict__ w1,
                        const float* __restrict__ b1, us* __restrict__ y1T){
    __shared__ float w[320];
    __shared__ float bb[32];
    int t = threadIdx.x;
    for(int i=t;i<320;i+=256) w[i] = w1[i];
    if(t < 32) bb[t] = b1[t];
    __syncthreads();
    int gid = blockIdx.x*256 + t;
    int node = gid>>5, p = gid&31;
    us* yo = y1T + (size_t)node*1024 + p*32;
    if(p >= 31){
        uint4 z = {0,0,0,0};
        *(uint4*)yo = z; *(uint4*)(yo+8) = z;
        *(uint4*)(yo+16) = z; *(uint4*)(yo+24) = z;
        return;
    }
    const float* xr = x + node*100 + 3*p;
    float xv[10];
    #pragma unroll
    for(int k=0;k<10;k++) xv[k] = xr[k];
    float o[32];
    #pragma unroll
    for(int c=0;c<32;c++){
        float a = bb[c];
        #pragma unroll
        for(int k=0;k<10;k++) a = fmaf(w[c*10+k], xv[k], a);
        o[c] = fmaxf(a, 0.0f);
    }
    *(uint4*)yo      = pack8(o);
    *(uint4*)(yo+8)  = pack8(o+8);
    *(uint4*)(yo+16) = pack8(o+16);
    *(uint4*)(yo+24) = pack8(o+24);
}

__global__ void k_chanstats_T(const us* __restrict__ y, float* __restrict__ sq){
    int tid = blockIdx.x*256 + threadIdx.x;
    int slot = tid & 1023;
    int c = slot & 31;
    int node0 = tid >> 10;
    float s = 0.f, q = 0.f;
    for(int n=node0; n<NN; n+=64){
        float v = bf2f(y[(size_t)n*1024 + slot]);
        s += v; q = fmaf(v, v, q);
    }
    s += __shfl_xor(s, 32);
    q += __shfl_xor(q, 32);
    if((threadIdx.x & 63) < 32){
        atomicAdd(&sq[c], s);
        atomicAdd(&sq[32+c], q);
    }
}

template<int SLOTS, int PPC>
__global__ void k_chanstats_bf(const us* __restrict__ y, float* __restrict__ sq){
    int tid = blockIdx.x*blockDim.x + threadIdx.x;
    int slot = tid & (SLOTS-1);
    int node0 = tid / SLOTS;
    int nstride = (gridDim.x*blockDim.x) / SLOTS;
    int c = slot / PPC;
    float s = 0.f, q = 0.f;
    for(int n=node0; n<NN; n+=nstride){
        float v = bf2f(y[(size_t)n*SLOTS + slot]);
        s += v; q = fmaf(v, v, q);
    }
    #pragma unroll
    for(int m=PPC>>1; m>0; m>>=1){
        s += __shfl_xor(s, m);
        q += __shfl_xor(q, m);
    }
    if((threadIdx.x & (PPC-1)) == 0){
        atomicAdd(&sq[c], s);
        atomicAdd(&sq[32+c], q);
    }
}

__global__ void k_bnfin(const float* __restrict__ sq, const float* __restrict__ gamma,
                        const float* __restrict__ beta, float* __restrict__ scsh,
                        float inv_count){
    int c = threadIdx.x;
    if(c < 32){
        float m = sq[c]*inv_count;
        float v = sq[32+c]*inv_count - m*m;
        float sc = gamma[c]*rsqrtf(v + 1e-5f);
        scsh[c] = sc;
        scsh[32+c] = beta[c] - m*sc;
    }
}

// merged: blocks 0..39 fold BN1 into conv2 weights; block 40 computes bias
__global__ void k_wprep(const float* __restrict__ w2, const float* __restrict__ scsh1,
                        const float* __restrict__ b2, us* __restrict__ Bf,
                        float* __restrict__ biasc){
    int b = blockIdx.x;
    int t = threadIdx.x;
    if(b < 40){
        int idx = b*256 + t;
        int kk = idx >> 10, c2 = (idx >> 5) & 31, c = idx & 31;
        Bf[idx] = f2bf(scsh1[c] * w2[c2*320 + c*10 + kk]);
    }else{
        int c2 = t >> 3, part = t & 7;
        float s = 0.f;
        for(int i=part; i<320; i+=8)
            s += scsh1[32 + i/10] * w2[c2*320 + i];
        s += __shfl_xor(s,1); s += __shfl_xor(s,2); s += __shfl_xor(s,4);
        if(part == 0) biasc[c2] = b2[c2] + s;
    }
}

// conv2 via 10 shifted MFMAs
__global__ void __launch_bounds__(256) k_conv2m(const us* __restrict__ y1T,
        const us* __restrict__ Bf, const float* __restrict__ biasc,
        us* __restrict__ Xpre){
    int t = threadIdx.x;
    int wv = t>>6, l = t&63;
    int l15 = l&15, g = l>>4;
    int r0 = blockIdx.x*64 + wv*16;
    int arow = r0 + l15;
    int an = arow>>3, ap = arow&7;
    const us* abase = y1T + (size_t)an*1024 + (3*ap)*32 + g*8;
    const us* bbase = Bf + (size_t)l15*32 + g*8;
    f32x4 acc0 = {}, acc1 = {};
    #pragma unroll
    for(int kk=0;kk<10;kk++){
        s16x8 af = *(const s16x8*)(abase + kk*32);
        s16x8 b0 = *(const s16x8*)(bbase + kk*1024);
        s16x8 b1 = *(const s16x8*)(bbase + kk*1024 + 512);
        acc0 = __builtin_amdgcn_mfma_f32_16x16x32_bf16(af, b0, acc0, 0, 0, 0);
        acc1 = __builtin_amdgcn_mfma_f32_16x16x32_bf16(af, b1, acc1, 0, 0, 0);
    }
    int base = r0 + g*4;
    int n = base>>3, p0 = base&7;
    #pragma unroll
    for(int nf=0;nf<2;nf++){
        int c2 = nf*16 + l15;
        float bb = biasc[c2];
        f32x4 a = nf ? acc1 : acc0;
        float v0 = fmaxf(a[0]+bb,0.f), v1 = fmaxf(a[1]+bb,0.f);
        float v2 = fmaxf(a[2]+bb,0.f), v3 = fmaxf(a[3]+bb,0.f);
        uint2 pk;
        pk.x = ((unsigned)f2bf(v1)<<16)|f2bf(v0);
        pk.y = ((unsigned)f2bf(v3)<<16)|f2bf(v2);
        *(uint2*)&Xpre[(size_t)n*256 + c2*8 + p0] = pk;
    }
}

// build XHp [node][512]: chunk g: half0 = BN2(X)[g*8..], half1 = h0[g*8..]
__global__ void __launch_bounds__(256) k_prep(const us* __restrict__ Xpre,
        const float* __restrict__ scsh, const float* __restrict__ h0,
        us* __restrict__ XHp){
    int node = blockIdx.x*4 + (threadIdx.x>>6);
    if(node >= NN) return;
    int lane = threadIdx.x & 63;
    int half = lane>>5, g = lane&31;
    uint4 o;
    if(half == 0){
        uint4 v = *(const uint4*)(Xpre + (size_t)node*256 + g*8);
        float sc = scsh[g], sh = scsh[32+g];
        float y[8];
        y[0]=fmaf(sc,__uint_as_float(v.x<<16),sh); y[1]=fmaf(sc,__uint_as_float(v.x&0xffff0000u),sh);
        y[2]=fmaf(sc,__uint_as_float(v.y<<16),sh); y[3]=fmaf(sc,__uint_as_float(v.y&0xffff0000u),sh);
        y[4]=fmaf(sc,__uint_as_float(v.z<<16),sh); y[5]=fmaf(sc,__uint_as_float(v.z&0xffff0000u),sh);
        y[6]=fmaf(sc,__uint_as_float(v.w<<16),sh); y[7]=fmaf(sc,__uint_as_float(v.w&0xffff0000u),sh);
        o = pack8(y);
    }else{
        float4 a = *(const float4*)(h0 + (size_t)node*256 + g*8);
        float4 b = *(const float4*)(h0 + (size_t)node*256 + g*8 + 4);
        float y[8] = {a.x,a.y,a.z,a.w,b.x,b.y,b.z,b.w};
        o = pack8(y);
    }
    *(uint4*)(XHp + (size_t)node*512 + (size_t)g*16 + half*8) = o;
}

// ---------------- effective weights (transposed bf16, coalesced via LDS) ----------------

__device__ __forceinline__ float weff_val(const float* W, int term, size_t base){
    const size_t S = 512*256;
    if(term==0)      return W[0*S+base] + W[3*S+base] - W[2*S+base] - W[5*S+base];
    else if(term==1) return W[1*S+base];
    else if(term==2) return W[4*S+base];
    else if(term==3) return 2.0f*W[2*S+base];
    else             return 2.0f*W[5*S+base];
}

template<int NCOL>
__global__ void __launch_bounds__(256) k_wefft(const float* __restrict__ Wa,
        const float* __restrict__ Wb, us* __restrict__ Wt){
    __shared__ float tile[64*65];
    int bx = blockIdx.x;
    constexpr int CT = NCOL/64;
    int kb = bx / (CT*4);
    int rem = bx % (CT*4);
    int ct = rem >> 2, rt = rem & 3;
    int col0 = ct*64, rr0 = rt*64;
    const float* W = (col0 < 256) ? Wa : Wb;
    int jb = col0 & 255;
    int term = kb >> 1, half = kb & 1;
    int t = threadIdx.x;
    int j_l = t & 63, r4 = t >> 6;
    #pragma unroll
    for(int it=0; it<16; it++){
        int rr_l = it*4 + r4;
        int row = half*256 + rr0 + rr_l;
        size_t base = (size_t)row*256 + jb + j_l;
        tile[j_l*65 + rr_l] = weff_val(W, term, base);
    }
    __syncthreads();
    int rr_w = t & 63;
    #pragma unroll
    for(int it=0; it<16; it++){
        int col_l = it*4 + r4;
        Wt[(size_t)(col0+col_l)*2560 + kb*256 + rr0 + rr_w] = f2bf(tile[col_l*65 + rr_w]);
    }
}

// ---------------- propagation ----------------

__global__ void __launch_bounds__(256) k_prop1(const us* __restrict__ XHp,
        const int* __restrict__ coloff, const int2* __restrict__ ew,
        const float* __restrict__ invdeg, us* __restrict__ T1op, us* __restrict__ T1ip){
    int node = blockIdx.x*4 + (threadIdx.x>>6);
    if(node >= NN) return;
    int lane = threadIdx.x & 63;
    size_t lo = (size_t)(lane&31)*16 + (lane>>5)*8;
    int s = __builtin_amdgcn_readfirstlane(coloff[node]);
    int e = __builtin_amdgcn_readfirstlane(coloff[node+1]);
    float ao[8]={0,0,0,0,0,0,0,0}, ai[8]={0,0,0,0,0,0,0,0};
    int j = s;
    for(; j+7 < e; j += 8){
        int2 ed[8]; uint4 v[8];
        #pragma unroll
        for(int i=0;i<8;i++) ed[i] = ew[j+i];
        #pragma unroll
        for(int i=0;i<8;i++) v[i] = *(const uint4*)(XHp+(size_t)ed[i].x*512+lo);
        #pragma unroll
        for(int i=0;i<8;i++) upd8(v[i], __int_as_float(ed[i].y), ao, ai);
    }
    for(; j < e; j++){
        int2 ed = ew[j];
        uint4 v = *(const uint4*)(XHp+(size_t)ed.x*512+lo);
        upd8(v, __int_as_float(ed.y), ao, ai);
    }
    float wi = invdeg[node];
    *(uint4*)(T1op+(size_t)node*512+lo) = pack8(ao);
    *(uint4*)(T1ip+(size_t)node*512+lo) = pack8s(ai,wi);
}

__global__ void __launch_bounds__(256) k_prop2(const us* __restrict__ T1op,
        const us* __restrict__ T1ip,
        const int* __restrict__ coloff, const int2* __restrict__ ew,
        const float* __restrict__ invdeg, us* __restrict__ P2op, us* __restrict__ P2ip){
    int node = blockIdx.x*4 + (threadIdx.x>>6);
    if(node >= NN) return;
    int lane = threadIdx.x & 63;
    size_t lo = (size_t)(lane&31)*16 + (lane>>5)*8;
    int s = __builtin_amdgcn_readfirstlane(coloff[node]);
    int e = __builtin_amdgcn_readfirstlane(coloff[node+1]);
    float ao[8]={0,0,0,0,0,0,0,0}, ai[8]={0,0,0,0,0,0,0,0};
    int j = s;
    for(; j+3 < e; j += 4){
        int2 ed[4]; uint4 va[4], vb[4];
        #pragma unroll
        for(int i=0;i<4;i++) ed[i] = ew[j+i];
        #pragma unroll
        for(int i=0;i<4;i++){
            size_t o = (size_t)ed[i].x*512+lo;
            va[i] = *(const uint4*)(T1op+o);
            vb[i] = *(const uint4*)(T1ip+o);
        }
        #pragma unroll
        for(int i=0;i<4;i++){
            updw(va[i], __int_as_float(ed[i].y), ao);
            updw(vb[i], 1.0f, ai);
        }
    }
    for(; j < e; j++){
        int2 ed = ew[j];
        size_t o = (size_t)ed.x*512+lo;
        updw(*(const uint4*)(T1op+o), __int_as_float(ed.y), ao);
        updw(*(const uint4*)(T1ip+o), 1.0f, ai);
    }
    float wi = invdeg[node];
    *(uint4*)(P2op+(size_t)node*512+lo) = pack8(ao);
    *(uint4*)(P2ip+(size_t)node*512+lo) = pack8s(ai,wi);
}

// q1: prop of dense RHb [node][256]; lane-halves take alternate edges, shfl combine.
__global__ void __launch_bounds__(256) k_propq1(const us* __restrict__ RHb,
        const int* __restrict__ coloff, const int2* __restrict__ ew,
        const float* __restrict__ invdeg, us* __restrict__ Q1p){
    int node = blockIdx.x*4 + (threadIdx.x>>6);
    if(node >= NN) return;
    int lane = threadIdx.x & 63;
    int half = lane>>5, g = lane&31;
    int s = __builtin_amdgcn_readfirstlane(coloff[node]);
    int e = __builtin_amdgcn_readfirstlane(coloff[node+1]);
    float ao[8]={0,0,0,0,0,0,0,0}, ai[8]={0,0,0,0,0,0,0,0};
    int j = s;
    for(; j+3 < e; j += 4){
        int2 e0 = ew[j+half], e1 = ew[j+2+half];
        uint4 v0 = *(const uint4*)(RHb+(size_t)e0.x*256+g*8);
        uint4 v1 = *(const uint4*)(RHb+(size_t)e1.x*256+g*8);
        upd8(v0, __int_as_float(e0.y), ao, ai);
        upd8(v1, __int_as_float(e1.y), ao, ai);
    }
    for(; j+1 < e; j += 2){
        int2 ed = ew[j+half];
        uint4 v = *(const uint4*)(RHb+(size_t)ed.x*256+g*8);
        upd8(v, __int_as_float(ed.y), ao, ai);
    }
    if(j < e && half == 0){
        int2 ed = ew[j];
        uint4 v = *(const uint4*)(RHb+(size_t)ed.x*256+g*8);
        upd8(v, __int_as_float(ed.y), ao, ai);
    }
    #pragma unroll
    for(int k=0;k<8;k++){
        ao[k] += __shfl_xor(ao[k],32);
        ai[k] += __shfl_xor(ai[k],32);
    }
    if(half == 0){
        float wi = invdeg[node];
        *(uint4*)(Q1p+(size_t)node*512+(size_t)g*16)   = pack8(ao);
        *(uint4*)(Q1p+(size_t)node*512+(size_t)g*16+8) = pack8s(ai,wi);
    }
}

// q2: prop of Q1p pair (o-half weighted, i-half plain + invdeg)
__global__ void __launch_bounds__(256) k_propu(const us* __restrict__ Yin,
        const int* __restrict__ coloff, const int2* __restrict__ ew,
        const float* __restrict__ invdeg, us* __restrict__ Pout){
    int node = blockIdx.x*4 + (threadIdx.x>>6);
    if(node >= NN) return;
    int lane = threadIdx.x & 63;
    int half = lane>>5;
    size_t lo = (size_t)(lane&31)*16 + half*8;
    int s = __builtin_amdgcn_readfirstlane(coloff[node]);
    int e = __builtin_amdgcn_readfirstlane(coloff[node+1]);
    float a[8]={0,0,0,0,0,0,0,0};
    int j = s;
    for(; j+7 < e; j += 8){
        int2 ed[8]; uint4 v[8];
        #pragma unroll
        for(int i=0;i<8;i++) ed[i] = ew[j+i];
        #pragma unroll
        for(int i=0;i<8;i++) v[i] = *(const uint4*)(Yin+(size_t)ed[i].x*512+lo);
        #pragma unroll
        for(int i=0;i<8;i++) updw(v[i], half ? 1.0f : __int_as_float(ed[i].y), a);
    }
    for(; j < e; j++){
        int2 ed = ew[j];
        uint4 v = *(const uint4*)(Yin+(size_t)ed.x*512+lo);
        updw(v, half ? 1.0f : __int_as_float(ed.y), a);
    }
    float sc = half ? invdeg[node] : 1.0f;
    *(uint4*)(Pout+(size_t)node*512+lo) = pack8s(a,sc);
}

// ---------------- bf16 MFMA GEMM: r8 geometry (128 x BNT), 2-buffer counted-vmcnt ----------------
// Grid 640: xcd=bid&7, s=bid>>3, cidx=s&3, r=(s>>2)*8+xcd (<157).

template<int MODE, int BNT>
__global__ void __launch_bounds__(256) k_gemm(const us* __restrict__ XG,
        const us* __restrict__ RG, const us* __restrict__ Wt,
        const float* __restrict__ bias0, const float* __restrict__ bias1,
        const float* __restrict__ h0, const float* __restrict__ Zin,
        float* __restrict__ out0, us* __restrict__ out1){
    constexpr int WN = BNT/32;
    constexpr int NB = BNT/64;          // B gl16 per thread per step
    __shared__ us As[2][4096];
    __shared__ us Bs[2][BNT*32];
    int t = threadIdx.x;
    int wid = t >> 6, lane = t & 63;
    int l15 = lane & 15, kg = lane >> 4;

    int bid = blockIdx.x;
    int xcd = bid & 7, sblk = bid >> 3;
    int cidx = sblk & 3, r = (sblk >> 2)*8 + xcd;
    if(r >= 157) return;
    int row0 = r*128, col0 = cidx*BNT;
    int rowbase = (wid >> 1)*64, colbase = (wid & 1)*(BNT/2);
    int swz = (l15 >> 1) & 3;

    int srA[2], sgA[2];
    size_t rowoffA[2];
    #pragma unroll
    for(int i=0;i<2;i++){
        int c = t + i*256;
        srA[i] = c >> 2;
        sgA[i] = (c & 3) ^ ((srA[i] >> 1) & 3);
        int gr = row0 + srA[i];
        gr = (gr < NN) ? gr : NN-1;
        rowoffA[i] = (size_t)gr*512 + (size_t)sgA[i]*16;
    }
    int srB[NB], sgB[NB];
    size_t coloffB[NB];
    #pragma unroll
    for(int i=0;i<NB;i++){
        int c = t + i*256;
        srB[i] = c >> 2;
        sgB[i] = (c & 3) ^ ((srB[i] >> 1) & 3);
        coloffB[i] = (size_t)(col0+srB[i])*2560 + (size_t)sgB[i]*8;
    }

    f32x4 acc[4][WN] = {};

    auto stage = [&](int buf, int s){
        int kb = s >> 3;
        int ktc = (s & 7) * 4;
        if(MODE == 1 && kb == 1){
            #pragma unroll
            for(int i=0;i<2;i++)
                gl16(RG + (rowoffA[i] >> 1) + (size_t)ktc*8, &As[buf][(t+i*256)*8]);
        }else{
            const us* Ap;
            if(MODE == 0){
                Ap = XG + (size_t)(kb >> 1) * SBUF + (size_t)(kb & 1) * 8;
            }else{
                if((kb & 1) == 0) Ap = XG + (size_t)(kb >> 1) * SBUF;
                else Ap = RG + (size_t)((kb + 1) >> 2) * SBUF + (size_t)(((kb + 1) >> 1) & 1) * 8;
            }
            #pragma unroll
            for(int i=0;i<2;i++)
                gl16(Ap + rowoffA[i] + (size_t)ktc*16, &As[buf][(t+i*256)*8]);
        }
        const us* Wp = Wt + (size_t)kb*256 + (s & 7)*32;
        #pragma unroll
        for(int i=0;i<NB;i++)
            gl16(Wp + coloffB[i], &Bs[buf][(t+i*256)*8]);
    };

    stage(0, 0);
    stage(1, 1);
    for(int step=0; step<80; ++step){
        int cur = step & 1;
        if(step < 79){
            if(MODE == 0) asm volatile("s_waitcnt vmcnt(4)" ::: "memory");
            else          asm volatile("s_waitcnt vmcnt(3)" ::: "memory");
        }else{
            asm volatile("s_waitcnt vmcnt(0)" ::: "memory");
        }
        __builtin_amdgcn_s_barrier();
        s16x8 af[4], bfr[WN];
        #pragma unroll
        for(int i=0;i<4;i++){
            int row = rowbase + i*16 + l15;
            af[i] = *(const s16x8*)&As[cur][(row*4 + (kg ^ swz))*8];
        }
        #pragma unroll
        for(int n=0;n<WN;n++){
            int colr = colbase + n*16 + l15;
            bfr[n] = *(const s16x8*)&Bs[cur][(colr*4 + (kg ^ swz))*8];
        }
        asm volatile("s_waitcnt lgkmcnt(0)" ::: "memory");
        __builtin_amdgcn_sched_barrier(0);
        __builtin_amdgcn_s_barrier();
        if(step < 78) stage(cur, step+2);
        __builtin_amdgcn_s_setprio(1);
        #pragma unroll
        for(int mi=0;mi<4;mi++){
            #pragma unroll
            for(int ni=0;ni<WN;ni++){
                acc[mi][ni] = __builtin_amdgcn_mfma_f32_16x16x32_bf16(
                    af[mi], bfr[ni], acc[mi][ni], 0, 0, 0);
            }
        }
        __builtin_amdgcn_s_setprio(0);
    }

    #pragma unroll
    for(int mi=0;mi<4;mi++){
        int gr0 = row0 + rowbase + mi*16 + kg*4;
        #pragma unroll
        for(int ni=0;ni<WN;ni++){
            int j = col0 + colbase + ni*16 + l15;
            #pragma unroll
            for(int rr=0;rr<4;rr++){
                int gr = gr0 + rr;
                if(gr < NN){
                    float a = acc[mi][ni][rr];
                    if(MODE == 0){
                        if(j < 256){
                            out0[(size_t)gr*256 + j] = 1.0f/(1.0f + expf(-(a + bias0[j])));
                        }else{
                            int jj = j - 256;
                            float rv = 1.0f/(1.0f + expf(-(a + bias1[jj])));
                            out1[(size_t)gr*256 + jj] = f2bf(rv * h0[(size_t)gr*256 + jj]);
                        }
                    }else{
                        float z = Zin[(size_t)gr*256 + j];
                        float ht = tanhf(a + bias0[j]);
                        float H = z*h0[(size_t)gr*256 + j] + (1.0f - z)*ht;
                        out0[(size_t)gr*256 + j] = fmaxf(H, 0.0f);
                    }
                }
            }
        }
    }
}

// ---------------- host ----------------

extern "C" void kernel_launch(void* const* d_in, const int* in_sizes, int n_in,
                              void* d_out, int out_size, void* d_ws, size_t ws_size,
                              hipStream_t stream){
    const float* x   = (const float*)d_in[0];
    const int*   ei  = (const int*)  d_in[1];
    const float* h0  = (const float*)d_in[2];
    const float* w1  = (const float*)d_in[3];
    const float* b1  = (const float*)d_in[4];
    const float* g1  = (const float*)d_in[5];
    const float* be1 = (const float*)d_in[6];
    const float* w2  = (const float*)d_in[7];
    const float* b2  = (const float*)d_in[8];
    const float* g2  = (const float*)d_in[9];
    const float* be2 = (const float*)d_in[10];
    const float* Wz  = (const float*)d_in[11];
    const float* bz  = (const float*)d_in[12];
    const float* Wr  = (const float*)d_in[13];
    const float* br  = (const float*)d_in[14];
    const float* Wh  = (const float*)d_in[15];
    const float* bh  = (const float*)d_in[16];
    float* out = (float*)d_out;
    float* wsf = (float*)d_ws;
    (void)in_sizes; (void)n_in; (void)out_size;

    // word (4B) offsets
    const size_t O_DEGO=0, O_DEGI=20000, O_CNT=40000, O_BN=60000;      // zero: 60256
    const size_t O_COLOFF=60288, O_EW=80384, O_INVDEG=720384;
    const size_t O_WTZR=740480, O_WTH=1395840;
    const size_t O_XPRE=1723520;
    const size_t O_XG=4283520;                 // 5 bufs x 5,120,000 words
    const size_t O_RG=29883520;                // RHb dense (2.56M) + Q1p + Q2p
    const size_t O_Z=45243520;                 // 20000x256 f32
    const size_t O_BF=50363520;                // conv2 folded weights
    const size_t WS_NEED_BYTES = (size_t)50366080 * 4;
    if(ws_size < WS_NEED_BYTES) return;

    const size_t SW = 5120000;

    int* degout = (int*)(wsf + O_DEGO);
    int* degin  = (int*)(wsf + O_DEGI);
    int* cnt    = (int*)(wsf + O_CNT);
    float* bn   = wsf + O_BN;
    int* coloff = (int*)(wsf + O_COLOFF);
    int2* ew    = (int2*)(wsf + O_EW);
    float* invdeg = wsf + O_INVDEG;
    us* Wtzr = (us*)(wsf + O_WTZR);
    us* Wth  = (us*)(wsf + O_WTH);
    us* Xpre = (us*)(wsf + O_XPRE);
    us* XG   = (us*)(wsf + O_XG);
    us* RG   = (us*)(wsf + O_RG);      // RHb dense [node][256]
    us* XHp  = XG;
    us* T1op = (us*)(wsf + O_XG + SW);
    us* T1ip = (us*)(wsf + O_XG + 2*SW);
    us* P2op = (us*)(wsf + O_XG + 3*SW);
    us* P2ip = (us*)(wsf + O_XG + 4*SW);
    us* RHb  = RG;
    us* Q1p  = (us*)(wsf + O_RG + SW);
    us* Q2p  = (us*)(wsf + O_RG + 2*SW);
    float* Z = wsf + O_Z;
    us* Bf   = (us*)(wsf + O_BF);
    us* y1T  = T1op;   // dead during CNN

    // graph CSR
    k_zero<<<236,256,0,stream>>>((uint32_t*)(wsf + O_DEGO), 60256);
    k_degree<<<1250,256,0,stream>>>(ei, degout, degin);
    k_scan<<<1,1024,0,stream>>>(degin, coloff, invdeg);
    k_csr<<<1250,256,0,stream>>>(ei, degout, coloff, cnt, ew);

    // CNN embedding
    k_conv1<<<2500,256,0,stream>>>(x, w1, b1, y1T);
    k_chanstats_T<<<256,256,0,stream>>>(y1T, bn+0);
    k_bnfin<<<1,32,0,stream>>>(bn+0, g1, be1, bn+64, 1.0f/620000.0f);
    k_wprep<<<41,256,0,stream>>>(w2, bn+64, b2, Bf, bn+256);
    k_conv2m<<<2500,256,0,stream>>>(y1T, Bf, bn+256, Xpre);
    k_chanstats_bf<256,8><<<64,256,0,stream>>>(Xpre, bn+128);
    k_bnfin<<<1,32,0,stream>>>(bn+128, g2, be2, bn+192, 1.0f/160000.0f);
    k_prep<<<5000,256,0,stream>>>(Xpre, bn+192, h0, XHp);

    // effective weights (transposed bf16, coalesced)
    k_wefft<512><<<320,256,0,stream>>>(Wz, Wr, Wtzr);
    k_wefft<256><<<160,256,0,stream>>>(Wh, Wh, Wth);

    // hop1 + hop2 props
    k_prop1<<<5000,256,0,stream>>>(XHp, coloff, ew, invdeg, T1op, T1ip);
    k_prop2<<<5000,256,0,stream>>>(T1op, T1ip, coloff, ew, invdeg, P2op, P2ip);

    // Z,R GEMM (fused sigmoid; RHb = bf16(sigmoid(r)*h0), dense 256)
    k_gemm<0,128><<<640,256,0,stream>>>(XG, RG, Wtzr, bz, br, h0, nullptr, Z, RHb);

    // props of RH
    k_propq1<<<5000,256,0,stream>>>(RHb, coloff, ew, invdeg, Q1p);
    k_propu<<<5000,256,0,stream>>>(Q1p, coloff, ew, invdeg, Q2p);

    // H~ GEMM (fused tanh + gate + relu -> out)
    k_gemm<1,64><<<640,256,0,stream>>>(XG, RG, Wth, bh, nullptr, h0, Z, out, nullptr);
}